// Round 14
// baseline (867.659 us; speedup 1.0000x reference)
//
#include <hip/hip_runtime.h>
#include <math.h>

#define EPS 1e-5f
#define MROWS 100352        // B_ * N = 1568 * 64
#define NWIN  1568

typedef __attribute__((ext_vector_type(8))) short bf16x8;
typedef __attribute__((ext_vector_type(4))) float f32x4;

__device__ __forceinline__ unsigned short f2bf(float f) {
  unsigned u = __float_as_uint(f);
  u += 0x7fffu + ((u >> 16) & 1u);
  return (unsigned short)(u >> 16);
}
__device__ __forceinline__ float bf2f(unsigned short s) {
  return __uint_as_float(((unsigned)s) << 16);
}
__device__ __forceinline__ float gelu_exact(float x) {
  return 0.5f * x * (1.f + erff(x * 0.70710678118654752f));
}

#define GLOAD16(gp, lp)                                              \
  __builtin_amdgcn_global_load_lds(                                  \
      (const __attribute__((address_space(1))) void*)(gp),           \
      (__attribute__((address_space(3))) void*)(lp), 16, 0, 0)

// ---------------------------------------------------------------------------
// 256x256-tile 8-phase bf16 MFMA GEMM, BK=32 variant: 64 KiB LDS total
// (2 buffers x (A 256x32 + B 256x32)) -> 2 blocks/CU for cross-block
// latency hiding (was 128 KiB -> 1 block/CU, ~94% stall per block).
// Swizzle: byte ^= (row&3)<<4 within the 64-B row (2-bit XOR max at 16-B
// read granularity). One GLOAD16 per half-tile -> counted vmcnt(1) at p0.
// ---------------------------------------------------------------------------
__device__ __forceinline__ void stage_half32(
    const unsigned short* __restrict__ base, int r0, int K, int kk,
    unsigned short* lds, int ldsbase, int tid) {
  int r = tid >> 2;                                // local row 0..127
  int cb = ((tid & 3) << 4) ^ ((r & 3) << 4);      // inverse-swizzled byte col
  const unsigned short* src = base + (size_t)(r0 + r) * K + kk + (cb >> 1);
  GLOAD16(src, &lds[ldsbase + tid * 8]);
}

__device__ __forceinline__ bf16x8 frag_read32(const unsigned short* lds,
                                              int tilebase, int r_t, int cbyte) {
  int off = r_t * 64 + cbyte;
  int phys = off ^ ((r_t & 3) << 4);
  return *(const bf16x8*)&lds[tilebase + (phys >> 1)];
}

template <bool OUTBF>
__global__ __launch_bounds__(512) void gemm256(
    const unsigned short* __restrict__ A, const unsigned short* __restrict__ Bt,
    const float* __restrict__ bias, void* __restrict__ Cout,
    int M, int N, int K) {
  __shared__ unsigned short lds[32768];  // 64 KiB
  const int tid = threadIdx.x;
  const int lane = tid & 63, wave = tid >> 6;
  const int wr = wave >> 2, wcn = wave & 3;
  int bx, by;
  {
    const int nwg = gridDim.x * gridDim.y;
    int n = blockIdx.y * gridDim.x + blockIdx.x;
    int w = ((nwg & 7) == 0) ? ((n & 7) * (nwg >> 3) + (n >> 3)) : n;
    by = w / gridDim.x;
    bx = w - by * gridDim.x;
  }
  const int row0 = by * 256, col0 = bx * 256;
  const int rl = lane & 15, qd = lane >> 4;
  f32x4 acc[8][4];
#pragma unroll
  for (int m = 0; m < 8; ++m)
#pragma unroll
    for (int n = 0; n < 4; ++n) acc[m][n] = (f32x4){0.f, 0.f, 0.f, 0.f};

  const int KT = K >> 5;
  // prologue: stage K-tile 0 into buffer 0 (4 gload insts/thread-block)
  stage_half32(A, row0, K, 0, lds, 0, tid);
  stage_half32(A, row0 + 128, K, 0, lds, 4096, tid);
  stage_half32(Bt, col0, K, 0, lds, 8192, tid);
  stage_half32(Bt, col0 + 128, K, 0, lds, 12288, tid);

  for (int kt = 0; kt < KT; ++kt) {
    const int b = kt & 1;
    const int abase = b * 16384, bbase = b * 16384 + 8192;
    const int nb = b ^ 1;
    const int kkn = (kt + 1) << 5;
    const bool last = (kt == KT - 1);
    bf16x8 bfr[4];
#pragma unroll
    for (int p = 0; p < 4; ++p) {
      if (!last) {
        if (p == 0)      stage_half32(A, row0, K, kkn, lds, nb * 16384, tid);
        else if (p == 1) stage_half32(A, row0 + 128, K, kkn, lds, nb * 16384 + 4096, tid);
        else if (p == 2) stage_half32(Bt, col0, K, kkn, lds, nb * 16384 + 8192, tid);
        else             stage_half32(Bt, col0 + 128, K, kkn, lds, nb * 16384 + 12288, tid);
      }
      if (p == 0) {
        if (!last) asm volatile("s_waitcnt vmcnt(1)" ::: "memory");
        else       asm volatile("s_waitcnt vmcnt(0)" ::: "memory");
      }
      __builtin_amdgcn_s_barrier();
      __builtin_amdgcn_sched_barrier(0);
      if (p == 0) {
#pragma unroll
        for (int n = 0; n < 4; ++n)
          bfr[n] = frag_read32(lds, bbase, wcn * 64 + n * 16 + rl, qd * 16);
      }
      bf16x8 af[2];
#pragma unroll
      for (int i = 0; i < 2; ++i)
        af[i] = frag_read32(lds, abase, wr * 128 + (2 * p + i) * 16 + rl, qd * 16);
      __builtin_amdgcn_s_setprio(1);
#pragma unroll
      for (int i = 0; i < 2; ++i)
#pragma unroll
        for (int n = 0; n < 4; ++n)
          acc[2 * p + i][n] = __builtin_amdgcn_mfma_f32_16x16x32_bf16(
              af[i], bfr[n], acc[2 * p + i][n], 0, 0, 0);
      __builtin_amdgcn_s_setprio(0);
      __builtin_amdgcn_s_barrier();
    }
  }
  const int crow = qd * 4, ccol = rl;
#pragma unroll
  for (int n = 0; n < 4; ++n) {
    const int gc = col0 + wcn * 64 + n * 16 + ccol;
    const float bz = bias[gc];
#pragma unroll
    for (int m = 0; m < 8; ++m) {
      const int gr0 = row0 + wr * 128 + m * 16 + crow;
#pragma unroll
      for (int r = 0; r < 4; ++r) {
        float val = acc[m][n][r] + bz;
        if constexpr (OUTBF)
          ((unsigned short*)Cout)[(size_t)(gr0 + r) * N + gc] = f2bf(val);
        else
          ((float*)Cout)[(size_t)(gr0 + r) * N + gc] = val;
      }
    }
  }
}

// ---------------------------------------------------------------------------
// One fused prep kernel: weight transposes + bias pack + rel-pos bias table.
// ---------------------------------------------------------------------------
__device__ __forceinline__ void wtc(const float* in, unsigned short* out,
                                    int K, int N, int i) {
  if (i < K * N) {
    int n = i / K, k = i - n * K;
    out[i] = f2bf(in[(size_t)k * N + n]);
  }
}

__global__ __launch_bounds__(256) void prep_all(
    const float* __restrict__ w_pa, const float* __restrict__ w_pc,
    const float* __restrict__ pj_w, const float* __restrict__ w_qkv,
    const float* __restrict__ w_out, const float* __restrict__ si_w1,
    const float* __restrict__ b_pa, const float* __restrict__ b_pc,
    const float* __restrict__ rpb, const int* __restrict__ rel,
    unsigned short* __restrict__ WpaT, unsigned short* __restrict__ WpcT,
    unsigned short* __restrict__ PjT, unsigned short* __restrict__ QkvT,
    unsigned short* __restrict__ OutT, unsigned short* __restrict__ SiT,
    float* __restrict__ B12, float* __restrict__ biasf) {
  const int blk = blockIdx.x, t = threadIdx.x;
  if (blk < 512)        wtc(w_pa, WpaT, 512, 256, blk * 256 + t);
  else if (blk < 1536)  wtc(w_pc, WpcT, 512, 512, (blk - 512) * 256 + t);
  else if (blk < 2048)  wtc(pj_w, PjT, 512, 256, (blk - 1536) * 256 + t);
  else if (blk < 2816)  wtc(w_qkv, QkvT, 256, 768, (blk - 2048) * 256 + t);
  else if (blk < 3840)  wtc(w_out, OutT, 512, 512, (blk - 2816) * 256 + t);
  else if (blk < 3904)  wtc(si_w1, SiT, 256, 64, (blk - 3840) * 256 + t);
  else if (blk == 3904) { B12[t] = b_pa[t]; }
  else if (blk < 3907)  { int i = (blk - 3905) * 256 + t; if (i < 512) B12[256 + i] = b_pc[i]; }
  else {
    int i = (blk - 3907) * 256 + t;
    if (i < 4096) {
      int r = rel[i];
#pragma unroll
      for (int h = 0; h < 8; ++h) biasf[h * 4096 + i] = rpb[r * 8 + h];
    }
  }
}

// x (f32) -> bf16, 8 elems/thread.
__global__ __launch_bounds__(256) void cvt_bf16(const float* __restrict__ in,
                                                unsigned short* __restrict__ out,
                                                int n8) {
  int i = blockIdx.x * 256 + threadIdx.x;
  if (i >= n8) return;
  float4 a = ((const float4*)in)[i * 2];
  float4 b = ((const float4*)in)[i * 2 + 1];
  ((ushort4*)out)[i * 2] = make_ushort4(f2bf(a.x), f2bf(a.y), f2bf(a.z), f2bf(a.w));
  ((ushort4*)out)[i * 2 + 1] = make_ushort4(f2bf(b.x), f2bf(b.y), f2bf(b.z), f2bf(b.w));
}

// ---------------------------------------------------------------------------
// Dual LayerNorm: one read of (M,768) row -> LN-256 out + LN-512 out.
// ---------------------------------------------------------------------------
__global__ __launch_bounds__(256) void ln_dual(
    const unsigned short* __restrict__ in,
    unsigned short* __restrict__ outa, unsigned short* __restrict__ outc,
    const float* __restrict__ ga, const float* __restrict__ ba,
    const float* __restrict__ gc, const float* __restrict__ bc) {
  const int row = blockIdx.x * 4 + (threadIdx.x >> 6);
  const int t = threadIdx.x & 63;
  const size_t ibase = (size_t)row * 768;
  float va[4], vc[8];
  {
    ushort4 u = *(const ushort4*)&in[ibase + t * 4];
    va[0] = bf2f(u.x); va[1] = bf2f(u.y); va[2] = bf2f(u.z); va[3] = bf2f(u.w);
    ushort4 u0 = *(const ushort4*)&in[ibase + 256 + t * 8];
    ushort4 u1 = *(const ushort4*)&in[ibase + 256 + t * 8 + 4];
    vc[0] = bf2f(u0.x); vc[1] = bf2f(u0.y); vc[2] = bf2f(u0.z); vc[3] = bf2f(u0.w);
    vc[4] = bf2f(u1.x); vc[5] = bf2f(u1.y); vc[6] = bf2f(u1.z); vc[7] = bf2f(u1.w);
  }
  float sa = va[0] + va[1] + va[2] + va[3];
  float qa = va[0]*va[0] + va[1]*va[1] + va[2]*va[2] + va[3]*va[3];
  float sc = 0.f, qc = 0.f;
#pragma unroll
  for (int j = 0; j < 8; ++j) { sc += vc[j]; qc += vc[j] * vc[j]; }
#pragma unroll
  for (int off = 32; off >= 1; off >>= 1) {
    sa += __shfl_xor(sa, off); qa += __shfl_xor(qa, off);
    sc += __shfl_xor(sc, off); qc += __shfl_xor(qc, off);
  }
  const float ma = sa * (1.f / 256.f);
  const float ra = rsqrtf(qa * (1.f / 256.f) - ma * ma + EPS);
  const float mc = sc * (1.f / 512.f);
  const float rc = rsqrtf(qc * (1.f / 512.f) - mc * mc + EPS);
  {
    int c = t * 4;
    *(ushort4*)&outa[(size_t)row * 256 + c] = make_ushort4(
        f2bf((va[0] - ma) * ra * ga[c + 0] + ba[c + 0]),
        f2bf((va[1] - ma) * ra * ga[c + 1] + ba[c + 1]),
        f2bf((va[2] - ma) * ra * ga[c + 2] + ba[c + 2]),
        f2bf((va[3] - ma) * ra * ga[c + 3] + ba[c + 3]));
  }
#pragma unroll
  for (int half = 0; half < 2; ++half) {
    int c = t * 8 + half * 4;
    *(ushort4*)&outc[(size_t)row * 512 + c] = make_ushort4(
        f2bf((vc[half * 4 + 0] - mc) * rc * gc[c + 0] + bc[c + 0]),
        f2bf((vc[half * 4 + 1] - mc) * rc * gc[c + 1] + bc[c + 1]),
        f2bf((vc[half * 4 + 2] - mc) * rc * gc[c + 2] + bc[c + 2]),
        f2bf((vc[half * 4 + 3] - mc) * rc * gc[c + 3] + bc[c + 3]));
  }
}

// ---------------------------------------------------------------------------
// Depthwise 3x3 + BN1 + GELU, bf16 LDS tile, vectorized staging.
// ---------------------------------------------------------------------------
__global__ __launch_bounds__(256) void dwconv_bn_gelu(
    const unsigned short* __restrict__ xin, const float* __restrict__ wgt9,
    const float* __restrict__ dwb, const float* __restrict__ g1,
    const float* __restrict__ b1, const float* __restrict__ m1,
    const float* __restrict__ v1, unsigned short* __restrict__ outp,
    float* __restrict__ ci_part) {
  __shared__ unsigned short tile[100 * 128];
  __shared__ float psum[8 * 128];
  const int b_ = blockIdx.x;
  const int b = b_ / 784, win = b_ % 784;
  const int wi = win / 28, wj = win % 28;
  const int h0 = wi * 8 - 1, w0 = wj * 8 - 1;
  const int tid = threadIdx.x;
  const int c4 = (tid & 31) * 4;
  const int pg = tid >> 5;
  for (int chunk = 0; chunk < 4; ++chunk) {
    const int c0 = chunk * 128;
    __syncthreads();
#pragma unroll
    for (int it = 0; it < 7; ++it) {
      int idx = it * 256 + tid;
      if (idx < 1600) {
        int p = idx >> 4;
        int ch8 = (idx & 15) * 8;
        int ph = h0 + p / 10, pw = w0 + p % 10;
        uint4 val = {0u, 0u, 0u, 0u};
        if (ph >= 0 && ph < 224 && pw >= 0 && pw < 224) {
          int bs = b * 784 + (ph >> 3) * 28 + (pw >> 3);
          int n = ((ph & 7) << 3) | (pw & 7);
          val = *(const uint4*)&xin[(size_t)(bs * 64 + n) * 512 + c0 + ch8];
        }
        *(uint4*)&tile[p * 128 + ch8] = val;
      }
    }
    __syncthreads();
    float wreg[9][4];
    float scale[4], shift[4], bias0[4];
#pragma unroll
    for (int j = 0; j < 4; ++j) {
      int cc = c0 + c4 + j;
#pragma unroll
      for (int k = 0; k < 9; ++k) wreg[k][j] = wgt9[cc * 9 + k];
      scale[j] = g1[cc] * rsqrtf(v1[cc] + EPS);
      shift[j] = b1[cc] - m1[cc] * scale[j];
      bias0[j] = dwb[cc];
    }
    float cs0 = 0.f, cs1 = 0.f, cs2 = 0.f, cs3 = 0.f;
    for (int q = 0; q < 8; ++q) {
      const int qq = pg * 8 + q;
      const int r = qq >> 3, cc_ = qq & 7;
      float a0 = bias0[0], a1 = bias0[1], a2 = bias0[2], a3 = bias0[3];
#pragma unroll
      for (int dr = 0; dr < 3; ++dr)
#pragma unroll
        for (int dc = 0; dc < 3; ++dc) {
          ushort4 u = *(const ushort4*)&tile[((r + dr) * 10 + cc_ + dc) * 128 + c4];
          const int k = dr * 3 + dc;
          a0 += bf2f(u.x) * wreg[k][0];
          a1 += bf2f(u.y) * wreg[k][1];
          a2 += bf2f(u.z) * wreg[k][2];
          a3 += bf2f(u.w) * wreg[k][3];
        }
      float g0 = gelu_exact(a0 * scale[0] + shift[0]);
      float g1v = gelu_exact(a1 * scale[1] + shift[1]);
      float g2v = gelu_exact(a2 * scale[2] + shift[2]);
      float g3v = gelu_exact(a3 * scale[3] + shift[3]);
      cs0 += g0; cs1 += g1v; cs2 += g2v; cs3 += g3v;
      *(ushort4*)&outp[(size_t)(b_ * 64 + qq) * 512 + c0 + c4] =
          make_ushort4(f2bf(g0), f2bf(g1v), f2bf(g2v), f2bf(g3v));
    }
    *(float4*)&psum[pg * 128 + c4] = make_float4(cs0, cs1, cs2, cs3);
    __syncthreads();
    if (tid < 128) {
      float s = 0.f;
#pragma unroll
      for (int g = 0; g < 8; ++g) s += psum[g * 128 + tid];
      ci_part[(size_t)b_ * 512 + c0 + tid] = s;
    }
  }
}

__global__ __launch_bounds__(512) void ci_reduce(const float* __restrict__ ci_part,
                                                 float* __restrict__ ci_mean) {
  const int b = blockIdx.x, c = threadIdx.x;
  float s = 0.f;
  for (int w = 0; w < 784; ++w) s += ci_part[(size_t)(b * 784 + w) * 512 + c];
  ci_mean[b * 512 + c] = s * (1.f / 50176.f);
}

__global__ __launch_bounds__(512) void ci_gate(
    const float* __restrict__ ci_mean, const float* __restrict__ w1,
    const float* __restrict__ bi1, const float* __restrict__ g2,
    const float* __restrict__ b2, const float* __restrict__ m2,
    const float* __restrict__ v2, const float* __restrict__ w2,
    const float* __restrict__ bi2, float* __restrict__ gate) {
  __shared__ float cm[1024];
  __shared__ float c1[128];
  const int t = threadIdx.x;
  cm[t] = ci_mean[t];
  cm[t + 512] = ci_mean[t + 512];
  __syncthreads();
  if (t < 128) {
    int b = t >> 6, j = t & 63;
    float acc = bi1[j];
    for (int c = 0; c < 512; ++c) acc += cm[b * 512 + c] * w1[c * 64 + j];
    float sc = g2[j] * rsqrtf(v2[j] + EPS);
    c1[t] = gelu_exact((acc - m2[j]) * sc + b2[j]);
  }
  __syncthreads();
  {
    int b = t >> 8, o = t & 255;
    float acc = bi2[o];
#pragma unroll
    for (int j = 0; j < 64; ++j) acc += c1[b * 64 + j] * w2[j * 256 + o];
    gate[b * 256 + o] = 1.f / (1.f + expf(-acc));
  }
}

// ---------------------------------------------------------------------------
// Fused attention + si gate + BN3 + LN-out + concat (round-13 proven v3).
// ---------------------------------------------------------------------------
__global__ __launch_bounds__(256) void attn_si(
    const unsigned short* __restrict__ qkv,   // (M,768) bf16
    const unsigned short* __restrict__ xpj,   // (M,256) bf16
    const float* __restrict__ gate, const float* __restrict__ biasf,
    const unsigned short* __restrict__ siw1t, // (64,256) bf16 = si_w1^T
    const float* __restrict__ bi1, const float* __restrict__ g4,
    const float* __restrict__ b4v, const float* __restrict__ m4,
    const float* __restrict__ v4, const float* __restrict__ w2,
    const float* __restrict__ bi2,
    const float* __restrict__ g3, const float* __restrict__ b3v,
    const float* __restrict__ m3, const float* __restrict__ v3,
    const float* __restrict__ glno, const float* __restrict__ blno,
    unsigned short* __restrict__ outc) {      // (M,512) bf16
  __shared__ unsigned short smem[17920];  // 35840 B union
  __shared__ float sig[64];
  const int w = blockIdx.x;
  const int b = w / 784;
  const int tid = threadIdx.x, lane = tid & 63, wave = tid >> 6;
  unsigned short* vT = smem + wave * 4480;   // [32][68]
  unsigned short* ph = vT + 2176;            // [64][36]
  const int l15 = lane & 15, l4 = lane >> 4;
  const float scale = 0.17677669529663687f;
  f32x4 o0[4][2], o1[4][2];
#pragma unroll
  for (int hh = 0; hh < 2; ++hh) {
    const int h = wave * 2 + hh;
    {
      const float* gh = &gate[b * 256 + h * 32];
      const size_t vbase = ((size_t)w * 64 + lane) * 768 + 512 + h * 32;
#pragma unroll
      for (int c = 0; c < 4; ++c) {
        uint4 vv = *(const uint4*)&qkv[vbase + c * 8];
        float4 gA = *(const float4*)&gh[c * 8];
        float4 gB = *(const float4*)&gh[c * 8 + 4];
        unsigned vw[4] = {vv.x, vv.y, vv.z, vv.w};
        float gg[8] = {gA.x, gA.y, gA.z, gA.w, gB.x, gB.y, gB.z, gB.w};
#pragma unroll
        for (int j = 0; j < 4; ++j) {
          int d = c * 8 + j * 2;
          vT[(d + 0) * 68 + lane] = f2bf(__uint_as_float(vw[j] << 16) * gg[j * 2]);
          vT[(d + 1) * 68 + lane] =
              f2bf(__uint_as_float(vw[j] & 0xffff0000u) * gg[j * 2 + 1]);
        }
      }
    }
    bf16x8 kf[4], qf[4];
    const size_t qkbase = (size_t)w * 64 * 768 + h * 32 + l4 * 8;
#pragma unroll
    for (int t = 0; t < 4; ++t) {
      kf[t] = *(const bf16x8*)&qkv[qkbase + (size_t)(t * 16 + l15) * 768 + 256];
      qf[t] = *(const bf16x8*)&qkv[qkbase + (size_t)(t * 16 + l15) * 768];
    }
    f32x4 s[4][4];
#pragma unroll
    for (int mt = 0; mt < 4; ++mt)
#pragma unroll
      for (int nt = 0; nt < 4; ++nt) s[mt][nt] = (f32x4){0.f, 0.f, 0.f, 0.f};
#pragma unroll
    for (int mt = 0; mt < 4; ++mt)
#pragma unroll
      for (int nt = 0; nt < 4; ++nt)
        s[mt][nt] = __builtin_amdgcn_mfma_f32_16x16x32_bf16(kf[mt], qf[nt],
                                                            s[mt][nt], 0, 0, 0);
    float inv_s[4];
#pragma unroll
    for (int nt = 0; nt < 4; ++nt) {
      float mx = -1e30f;
#pragma unroll
      for (int mt = 0; mt < 4; ++mt) {
        float4 b4 = *(const float4*)&biasf[(h * 64 + nt * 16 + l15) * 64 +
                                           mt * 16 + l4 * 4];
        s[mt][nt][0] = s[mt][nt][0] * scale + b4.x;
        s[mt][nt][1] = s[mt][nt][1] * scale + b4.y;
        s[mt][nt][2] = s[mt][nt][2] * scale + b4.z;
        s[mt][nt][3] = s[mt][nt][3] * scale + b4.w;
#pragma unroll
        for (int r = 0; r < 4; ++r) mx = fmaxf(mx, s[mt][nt][r]);
      }
      mx = fmaxf(mx, __shfl_xor(mx, 16));
      mx = fmaxf(mx, __shfl_xor(mx, 32));
      float sum = 0.f;
#pragma unroll
      for (int mt = 0; mt < 4; ++mt)
#pragma unroll
        for (int r = 0; r < 4; ++r) {
          float e = __expf(s[mt][nt][r] - mx);
          s[mt][nt][r] = e;
          sum += e;
        }
      sum += __shfl_xor(sum, 16);
      sum += __shfl_xor(sum, 32);
      inv_s[nt] = 1.f / sum;
    }
#pragma unroll
    for (int i = 0; i < 4; ++i)
#pragma unroll
      for (int dt = 0; dt < 2; ++dt)
        (hh ? o1 : o0)[i][dt] = (f32x4){0.f, 0.f, 0.f, 0.f};
#pragma unroll
    for (int ks = 0; ks < 2; ++ks) {
#pragma unroll
      for (int nt = 0; nt < 4; ++nt)
#pragma unroll
        for (int mh = 0; mh < 2; ++mh) {
          const int mt = 2 * ks + mh;
          ushort4 pk = make_ushort4(f2bf(s[mt][nt][0] * inv_s[nt]),
                                    f2bf(s[mt][nt][1] * inv_s[nt]),
                                    f2bf(s[mt][nt][2] * inv_s[nt]),
                                    f2bf(s[mt][nt][3] * inv_s[nt]));
          *(ushort4*)&ph[(nt * 16 + l15) * 36 + mh * 16 + l4 * 4] = pk;
        }
      bf16x8 pa[4], vf[2];
#pragma unroll
      for (int i = 0; i < 4; ++i) {
        const unsigned short* pp = &ph[(i * 16 + l15) * 36 + l4 * 8];
        union { bf16x8 v; ushort4 u[2]; } tmp;
        tmp.u[0] = *(const ushort4*)pp;
        tmp.u[1] = *(const ushort4*)(pp + 4);
        pa[i] = tmp.v;
      }
#pragma unroll
      for (int dt = 0; dt < 2; ++dt) {
        const unsigned short* vp = &vT[(dt * 16 + l15) * 68 + ks * 32 + l4 * 8];
        union { bf16x8 v; ushort4 u[2]; } tmp;
        tmp.u[0] = *(const ushort4*)vp;
        tmp.u[1] = *(const ushort4*)(vp + 4);
        vf[dt] = tmp.v;
      }
#pragma unroll
      for (int i = 0; i < 4; ++i)
#pragma unroll
        for (int dt = 0; dt < 2; ++dt)
          (hh ? o1 : o0)[i][dt] = __builtin_amdgcn_mfma_f32_16x16x32_bf16(
              pa[i], vf[dt], (hh ? o1 : o0)[i][dt], 0, 0, 0);
    }
  }
  __syncthreads();
  unsigned short* xattO = smem;
#pragma unroll
  for (int hh = 0; hh < 2; ++hh) {
    const int h = wave * 2 + hh;
#pragma unroll
    for (int i = 0; i < 4; ++i)
#pragma unroll
      for (int dt = 0; dt < 2; ++dt)
#pragma unroll
        for (int r = 0; r < 4; ++r)
          xattO[(i * 16 + l4 * 4 + r) * 264 + h * 32 + dt * 16 + l15] =
              f2bf((hh ? o1 : o0)[i][dt][r]);
  }
  __syncthreads();
  {
    f32x4 a4[4];
#pragma unroll
    for (int n = 0; n < 4; ++n) a4[n] = (f32x4){0.f, 0.f, 0.f, 0.f};
#pragma unroll
    for (int ks = 0; ks < 8; ++ks) {
      bf16x8 af = *(const bf16x8*)&xattO[(wave * 16 + l15) * 264 + ks * 32 + l4 * 8];
#pragma unroll
      for (int n = 0; n < 4; ++n) {
        bf16x8 bfr = *(const bf16x8*)&siw1t[(n * 16 + l15) * 256 + ks * 32 + l4 * 8];
        a4[n] = __builtin_amdgcn_mfma_f32_16x16x32_bf16(af, bfr, a4[n], 0, 0, 0);
      }
    }
    float part[4] = {0.f, 0.f, 0.f, 0.f};
#pragma unroll
    for (int n = 0; n < 4; ++n) {
      const int j = n * 16 + l15;
      const float sc4 = g4[j] * rsqrtf(v4[j] + EPS);
      const float m4j = m4[j], b4j = b4v[j], bij = bi1[j], w2j = w2[j];
#pragma unroll
      for (int r = 0; r < 4; ++r)
        part[r] += gelu_exact((a4[n][r] + bij - m4j) * sc4 + b4j) * w2j;
    }
#pragma unroll
    for (int r = 0; r < 4; ++r) {
      part[r] += __shfl_xor(part[r], 1);
      part[r] += __shfl_xor(part[r], 2);
      part[r] += __shfl_xor(part[r], 4);
      part[r] += __shfl_xor(part[r], 8);
    }
    if (l15 == 0) {
      const float b2v = bi2[0];
#pragma unroll
      for (int r = 0; r < 4; ++r)
        sig[wave * 16 + l4 * 4 + r] = 1.f / (1.f + expf(-(part[r] + b2v)));
    }
  }
  __syncthreads();
  {
    const int p = tid >> 2, l = tid & 3;
    float s = 0.f, sq = 0.f;
#pragma unroll
    for (int k = 0; k < 16; ++k) {
      ushort4 u = *(const ushort4*)&xattO[p * 264 + l * 4 + k * 16];
      float x0 = bf2f(u.x), x1 = bf2f(u.y), x2 = bf2f(u.z), x3 = bf2f(u.w);
      s += x0 + x1 + x2 + x3;
      sq += x0 * x0 + x1 * x1 + x2 * x2 + x3 * x3;
    }
    s += __shfl_xor(s, 1);  sq += __shfl_xor(sq, 1);
    s += __shfl_xor(s, 2);  sq += __shfl_xor(sq, 2);
    const float mean = s * (1.f / 256.f);
    const float var = sq * (1.f / 256.f) - mean * mean;
    const float rstd = rsqrtf(var + EPS);
    const size_t orow = ((size_t)w * 64 + p) * 512;
    const float sg = sig[p];
#pragma unroll
    for (int k = 0; k < 16; ++k) {
      const int c = l * 4 + k * 16;
      ushort4 u = *(const ushort4*)&xattO[p * 264 + c];
      *(ushort4*)&outc[orow + c] = make_ushort4(
          f2bf((bf2f(u.x) - mean) * rstd * glno[c + 0] + blno[c + 0]),
          f2bf((bf2f(u.y) - mean) * rstd * glno[c + 1] + blno[c + 1]),
          f2bf((bf2f(u.z) - mean) * rstd * glno[c + 2] + blno[c + 2]),
          f2bf((bf2f(u.w) - mean) * rstd * glno[c + 3] + blno[c + 3]));
      ushort4 pu = *(const ushort4*)&xpj[((size_t)w * 64 + p) * 256 + c];
      float sc0 = g3[c + 0] * rsqrtf(v3[c + 0] + EPS);
      float sc1 = g3[c + 1] * rsqrtf(v3[c + 1] + EPS);
      float sc2 = g3[c + 2] * rsqrtf(v3[c + 2] + EPS);
      float sc3 = g3[c + 3] * rsqrtf(v3[c + 3] + EPS);
      *(ushort4*)&outc[orow + 256 + c] = make_ushort4(
          f2bf(sg * bf2f(pu.x) * sc0 + (b3v[c + 0] - m3[c + 0] * sc0)),
          f2bf(sg * bf2f(pu.y) * sc1 + (b3v[c + 1] - m3[c + 1] * sc1)),
          f2bf(sg * bf2f(pu.z) * sc2 + (b3v[c + 2] - m3[c + 2] * sc2)),
          f2bf(sg * bf2f(pu.w) * sc3 + (b3v[c + 3] - m3[c + 3] * sc3)));
    }
  }
}

// ---------------------------------------------------------------------------
extern "C" void kernel_launch(void* const* d_in, const int* in_sizes, int n_in,
                              void* d_out, int out_size, void* d_ws, size_t ws_size,
                              hipStream_t stream) {
  const float* x     = (const float*)d_in[0];
  const float* w_pa  = (const float*)d_in[1];
  const float* b_pa  = (const float*)d_in[2];
  const float* g_lna = (const float*)d_in[3];
  const float* b_lna = (const float*)d_in[4];
  const float* w_pc  = (const float*)d_in[5];
  const float* b_pc  = (const float*)d_in[6];
  const float* g_lnc = (const float*)d_in[7];
  const float* b_lnc = (const float*)d_in[8];
  const float* dw_w  = (const float*)d_in[9];
  const float* dw_b  = (const float*)d_in[10];
  const float* g_bn1 = (const float*)d_in[11];
  const float* b_bn1 = (const float*)d_in[12];
  const float* m_bn1 = (const float*)d_in[13];
  const float* v_bn1 = (const float*)d_in[14];
  const float* ci_w1 = (const float*)d_in[15];
  const float* ci_b1 = (const float*)d_in[16];
  const float* g_bn2 = (const float*)d_in[17];
  const float* b_bn2 = (const float*)d_in[18];
  const float* m_bn2 = (const float*)d_in[19];
  const float* v_bn2 = (const float*)d_in[20];
  const float* ci_w2 = (const float*)d_in[21];
  const float* ci_b2 = (const float*)d_in[22];
  const float* pj_w  = (const float*)d_in[23];
  const float* pj_b  = (const float*)d_in[24];
  const float* g_bn3 = (const float*)d_in[25];
  const float* b_bn3 = (const float*)d_in[26];
  const float* m_bn3 = (const float*)d_in[27];
  const float* v_bn3 = (const float*)d_in[28];
  const float* w_qkv = (const float*)d_in[29];
  const float* b_qkv = (const float*)d_in[30];
  const float* si_w1 = (const float*)d_in[31];
  const float* si_b1 = (const float*)d_in[32];
  const float* g_bn4 = (const float*)d_in[33];
  const float* b_bn4 = (const float*)d_in[34];
  const float* m_bn4 = (const float*)d_in[35];
  const float* v_bn4 = (const float*)d_in[36];
  const float* si_w2 = (const float*)d_in[37];
  const float* si_b2 = (const float*)d_in[38];
  const float* g_lno = (const float*)d_in[39];
  const float* b_lno = (const float*)d_in[40];
  const float* w_out = (const float*)d_in[41];
  const float* b_out = (const float*)d_in[42];
  const float* rpb   = (const float*)d_in[43];
  const int*   rel   = (const int*)d_in[44];

  char* ws = (char*)d_ws;
  unsigned short* G12BF = (unsigned short*)(ws + 0);            // (M,768)
  unsigned short* QKVBF = (unsigned short*)(ws + 0);            // (M,768)
  unsigned short* A1BF  = (unsigned short*)(ws + 154140672ull); // (M,256)
  unsigned short* C1BF  = (unsigned short*)(ws + 205520896ull); // (M,512)
  unsigned short* CAT   = (unsigned short*)(ws + 205520896ull); // (M,512)
  unsigned short* XBF   = (unsigned short*)(ws + 308281344ull); // (M,512)
  unsigned short* CVBF  = (unsigned short*)(ws + 308281344ull); // (M,512)
  unsigned short* PJBF  = (unsigned short*)(ws + 411041792ull); // (M,256)
  float*          CIP   = (float*)(ws + 462422016ull);          // (1568,512)
  float*          CIM   = (float*)(ws + 465633280ull);          // (2,512)
  float*          GATE  = (float*)(ws + 465637376ull);          // (2,256)
  float*          B12   = (float*)(ws + 465639424ull);          // (768)
  float*          BIASF = (float*)(ws + 465642496ull);          // (8,64,64)
  unsigned short* WT    = (unsigned short*)(ws + 465773568ull);
  unsigned short* WpaT  = WT + 0;        // (256,512)
  unsigned short* WpcT  = WT + 131072;   // (512,512)
  unsigned short* PjT   = WT + 393216;   // (256,512)
  unsigned short* QkvT  = WT + 524288;   // (768,256)
  unsigned short* OutT  = WT + 720896;   // (512,512)
  unsigned short* SiT   = WT + 983040;   // (64,256)

  const int M = MROWS;
  dim3 b256(256), b512(512);

  // 0) fused prep + x->bf16
  prep_all<<<3923, b256, 0, stream>>>(w_pa, w_pc, pj_w, w_qkv, w_out, si_w1,
                                      b_pa, b_pc, rpb, rel,
                                      WpaT, WpcT, PjT, QkvT, OutT, SiT,
                                      B12, BIASF);
  cvt_bf16<<<(M * 512 / 8 + 255) / 256, b256, 0, stream>>>(x, XBF, M * 512 / 8);

  // 1+2) fused input GEMM: [x@w_pa | x@w_pc] -> G12BF (M,768)
  gemm256<true><<<dim3(3, M / 256), dim3(512), 0, stream>>>(XBF, WpaT, B12, G12BF,
                                                            M, 768, 512);
  ln_dual<<<M / 4, b256, 0, stream>>>(G12BF, A1BF, C1BF, g_lna, b_lna, g_lnc, b_lnc);

  // 3) depthwise conv + BN1 + GELU + channel sums (XBF dead -> CVBF)
  dwconv_bn_gelu<<<NWIN, b256, 0, stream>>>(C1BF, dw_w, dw_b, g_bn1, b_bn1, m_bn1,
                                            v_bn1, CVBF, CIP);
  ci_reduce<<<2, b512, 0, stream>>>(CIP, CIM);
  ci_gate<<<1, b512, 0, stream>>>(CIM, ci_w1, ci_b1, g_bn2, b_bn2, m_bn2, v_bn2,
                                  ci_w2, ci_b2, GATE);

  // 4) pj GEMM (bf16 out)
  gemm256<true><<<dim3(1, M / 256), dim3(512), 0, stream>>>(CVBF, PjT, pj_b, PJBF,
                                                            M, 256, 512);

  // 5) qkv GEMM (bf16 out; G12BF dead -> QKVBF)
  gemm256<true><<<dim3(3, M / 256), dim3(512), 0, stream>>>(A1BF, QkvT, b_qkv, QKVBF,
                                                            M, 768, 256);

  // 6) fused attention + si gate + BN3 + LN + concat (C1BF dead -> CAT)
  attn_si<<<NWIN, b256, 0, stream>>>(QKVBF, PJBF, GATE, BIASF, SiT,
                                     si_b1, g_bn4, b_bn4, m_bn4, v_bn4,
                                     si_w2, si_b2,
                                     g_bn3, b_bn3, m_bn3, v_bn3,
                                     g_lno, b_lno, CAT);

  // 7) final GEMM -> d_out (f32)
  gemm256<false><<<dim3(2, M / 256), dim3(512), 0, stream>>>(CAT, OutT, b_out,
                                                             (float*)d_out, M, 512, 512);
}

// Round 16
// 816.417 us; speedup vs baseline: 1.0628x; 1.0628x over previous
//
#include <hip/hip_runtime.h>
#include <math.h>

#define EPS 1e-5f
#define MROWS 100352        // B_ * N = 1568 * 64
#define NWIN  1568

typedef __attribute__((ext_vector_type(8))) short bf16x8;
typedef __attribute__((ext_vector_type(4))) float f32x4;

__device__ __forceinline__ unsigned short f2bf(float f) {
  unsigned u = __float_as_uint(f);
  u += 0x7fffu + ((u >> 16) & 1u);
  return (unsigned short)(u >> 16);
}
__device__ __forceinline__ float bf2f(unsigned short s) {
  return __uint_as_float(((unsigned)s) << 16);
}
__device__ __forceinline__ float gelu_exact(float x) {
  return 0.5f * x * (1.f + erff(x * 0.70710678118654752f));
}

#define GLOAD16(gp, lp)                                              \
  __builtin_amdgcn_global_load_lds(                                  \
      (const __attribute__((address_space(1))) void*)(gp),           \
      (__attribute__((address_space(3))) void*)(lp), 16, 0, 0)

// ---------------------------------------------------------------------------
// 256x256-tile 8-phase bf16 MFMA GEMM (proven BK=64 round-7 version).
// ---------------------------------------------------------------------------
__device__ __forceinline__ void stage_half256(
    const unsigned short* __restrict__ base, int r0, int K, int kk,
    unsigned short* lds, int ldsbase, int tid) {
#pragma unroll
  for (int inst = 0; inst < 2; ++inst) {
    int r = inst * 64 + (tid >> 3);
    int cb = ((tid & 7) << 4) ^ ((r & 7) << 4);
    const unsigned short* src = base + (size_t)(r0 + r) * K + kk + (cb >> 1);
    GLOAD16(src, &lds[ldsbase + inst * 4096 + tid * 8]);
  }
}

__device__ __forceinline__ bf16x8 frag_read256(const unsigned short* lds,
                                               int tilebase, int r_t, int cbyte) {
  int off = r_t * 128 + cbyte;
  int phys = off ^ ((r_t & 7) << 4);
  return *(const bf16x8*)&lds[tilebase + (phys >> 1)];
}

template <bool OUTBF>
__global__ __launch_bounds__(512) void gemm256(
    const unsigned short* __restrict__ A, const unsigned short* __restrict__ Bt,
    const float* __restrict__ bias, void* __restrict__ Cout,
    int M, int N, int K) {
  __shared__ unsigned short lds[65536];
  const int tid = threadIdx.x;
  const int lane = tid & 63, wave = tid >> 6;
  const int wr = wave >> 2, wcn = wave & 3;
  int bx, by;
  {
    const int nwg = gridDim.x * gridDim.y;
    int n = blockIdx.y * gridDim.x + blockIdx.x;
    int w = ((nwg & 7) == 0) ? ((n & 7) * (nwg >> 3) + (n >> 3)) : n;
    by = w / gridDim.x;
    bx = w - by * gridDim.x;
  }
  const int row0 = by * 256, col0 = bx * 256;
  const int rl = lane & 15, qd = lane >> 4;
  f32x4 acc[8][4];
#pragma unroll
  for (int m = 0; m < 8; ++m)
#pragma unroll
    for (int n = 0; n < 4; ++n) acc[m][n] = (f32x4){0.f, 0.f, 0.f, 0.f};

  const int KT = K >> 6;
  stage_half256(A, row0, K, 0, lds, 0, tid);
  stage_half256(A, row0 + 128, K, 0, lds, 8192, tid);
  stage_half256(Bt, col0, K, 0, lds, 16384, tid);
  stage_half256(Bt, col0 + 128, K, 0, lds, 24576, tid);

  for (int kt = 0; kt < KT; ++kt) {
    const int b = kt & 1;
    const int abase = b * 32768, bbase = b * 32768 + 16384;
    const int nb = b ^ 1;
    const int kkn = (kt + 1) << 6;
    const bool last = (kt == KT - 1);
    bf16x8 bfr[4][2];
#pragma unroll
    for (int p = 0; p < 4; ++p) {
      if (!last) {
        if (p == 0)      stage_half256(A, row0, K, kkn, lds, nb * 32768, tid);
        else if (p == 1) stage_half256(A, row0 + 128, K, kkn, lds, nb * 32768 + 8192, tid);
        else if (p == 2) stage_half256(Bt, col0, K, kkn, lds, nb * 32768 + 16384, tid);
        else             stage_half256(Bt, col0 + 128, K, kkn, lds, nb * 32768 + 24576, tid);
      }
      if (p == 0) {
        if (!last) asm volatile("s_waitcnt vmcnt(2)" ::: "memory");
        else       asm volatile("s_waitcnt vmcnt(0)" ::: "memory");
      }
      __builtin_amdgcn_s_barrier();
      __builtin_amdgcn_sched_barrier(0);
      if (p == 0) {
#pragma unroll
        for (int n = 0; n < 4; ++n)
#pragma unroll
          for (int ks = 0; ks < 2; ++ks)
            bfr[n][ks] = frag_read256(lds, bbase, wcn * 64 + n * 16 + rl,
                                      ks * 64 + qd * 16);
      }
      bf16x8 af[2][2];
#pragma unroll
      for (int i = 0; i < 2; ++i)
#pragma unroll
        for (int ks = 0; ks < 2; ++ks)
          af[i][ks] = frag_read256(lds, abase, wr * 128 + (2 * p + i) * 16 + rl,
                                   ks * 64 + qd * 16);
      __builtin_amdgcn_s_setprio(1);
#pragma unroll
      for (int i = 0; i < 2; ++i)
#pragma unroll
        for (int n = 0; n < 4; ++n)
#pragma unroll
          for (int ks = 0; ks < 2; ++ks)
            acc[2 * p + i][n] = __builtin_amdgcn_mfma_f32_16x16x32_bf16(
                af[i][ks], bfr[n][ks], acc[2 * p + i][n], 0, 0, 0);
      __builtin_amdgcn_s_setprio(0);
      __builtin_amdgcn_s_barrier();
    }
  }
  const int crow = qd * 4, ccol = rl;
#pragma unroll
  for (int n = 0; n < 4; ++n) {
    const int gc = col0 + wcn * 64 + n * 16 + ccol;
    const float bz = bias[gc];
#pragma unroll
    for (int m = 0; m < 8; ++m) {
      const int gr0 = row0 + wr * 128 + m * 16 + crow;
#pragma unroll
      for (int r = 0; r < 4; ++r) {
        float val = acc[m][n][r] + bz;
        if constexpr (OUTBF)
          ((unsigned short*)Cout)[(size_t)(gr0 + r) * N + gc] = f2bf(val);
        else
          ((float*)Cout)[(size_t)(gr0 + r) * N + gc] = val;
      }
    }
  }
}

// ---------------------------------------------------------------------------
// One fused prep kernel: weight transposes + bias pack + rel-pos bias table.
// ---------------------------------------------------------------------------
__device__ __forceinline__ void wtc(const float* in, unsigned short* out,
                                    int K, int N, int i) {
  if (i < K * N) {
    int n = i / K, k = i - n * K;
    out[i] = f2bf(in[(size_t)k * N + n]);
  }
}

__global__ __launch_bounds__(256) void prep_all(
    const float* __restrict__ w_pa, const float* __restrict__ w_pc,
    const float* __restrict__ pj_w, const float* __restrict__ w_qkv,
    const float* __restrict__ w_out, const float* __restrict__ si_w1,
    const float* __restrict__ b_pa, const float* __restrict__ b_pc,
    const float* __restrict__ rpb, const int* __restrict__ rel,
    unsigned short* __restrict__ WpaT, unsigned short* __restrict__ WpcT,
    unsigned short* __restrict__ PjT, unsigned short* __restrict__ QkvT,
    unsigned short* __restrict__ OutT, unsigned short* __restrict__ SiT,
    float* __restrict__ B12, float* __restrict__ biasf) {
  const int blk = blockIdx.x, t = threadIdx.x;
  if (blk < 512)        wtc(w_pa, WpaT, 512, 256, blk * 256 + t);
  else if (blk < 1536)  wtc(w_pc, WpcT, 512, 512, (blk - 512) * 256 + t);
  else if (blk < 2048)  wtc(pj_w, PjT, 512, 256, (blk - 1536) * 256 + t);
  else if (blk < 2816)  wtc(w_qkv, QkvT, 256, 768, (blk - 2048) * 256 + t);
  else if (blk < 3840)  wtc(w_out, OutT, 512, 512, (blk - 2816) * 256 + t);
  else if (blk < 3904)  wtc(si_w1, SiT, 256, 64, (blk - 3840) * 256 + t);
  else if (blk == 3904) { B12[t] = b_pa[t]; }
  else if (blk < 3907)  { int i = (blk - 3905) * 256 + t; if (i < 512) B12[256 + i] = b_pc[i]; }
  else {
    int i = (blk - 3907) * 256 + t;
    if (i < 4096) {
      int r = rel[i];
#pragma unroll
      for (int h = 0; h < 8; ++h) biasf[h * 4096 + i] = rpb[r * 8 + h];
    }
  }
}

// x (f32) -> bf16, 8 elems/thread.
__global__ __launch_bounds__(256) void cvt_bf16(const float* __restrict__ in,
                                                unsigned short* __restrict__ out,
                                                int n8) {
  int i = blockIdx.x * 256 + threadIdx.x;
  if (i >= n8) return;
  float4 a = ((const float4*)in)[i * 2];
  float4 b = ((const float4*)in)[i * 2 + 1];
  ((ushort4*)out)[i * 2] = make_ushort4(f2bf(a.x), f2bf(a.y), f2bf(a.z), f2bf(a.w));
  ((ushort4*)out)[i * 2 + 1] = make_ushort4(f2bf(b.x), f2bf(b.y), f2bf(b.z), f2bf(b.w));
}

// ---------------------------------------------------------------------------
// Dual LayerNorm: one read of (M,768) row -> LN-256 out + LN-512 out.
// ---------------------------------------------------------------------------
__global__ __launch_bounds__(256) void ln_dual(
    const unsigned short* __restrict__ in,
    unsigned short* __restrict__ outa, unsigned short* __restrict__ outc,
    const float* __restrict__ ga, const float* __restrict__ ba,
    const float* __restrict__ gc, const float* __restrict__ bc) {
  const int row = blockIdx.x * 4 + (threadIdx.x >> 6);
  const int t = threadIdx.x & 63;
  const size_t ibase = (size_t)row * 768;
  float va[4], vc[8];
  {
    ushort4 u = *(const ushort4*)&in[ibase + t * 4];
    va[0] = bf2f(u.x); va[1] = bf2f(u.y); va[2] = bf2f(u.z); va[3] = bf2f(u.w);
    ushort4 u0 = *(const ushort4*)&in[ibase + 256 + t * 8];
    ushort4 u1 = *(const ushort4*)&in[ibase + 256 + t * 8 + 4];
    vc[0] = bf2f(u0.x); vc[1] = bf2f(u0.y); vc[2] = bf2f(u0.z); vc[3] = bf2f(u0.w);
    vc[4] = bf2f(u1.x); vc[5] = bf2f(u1.y); vc[6] = bf2f(u1.z); vc[7] = bf2f(u1.w);
  }
  float sa = va[0] + va[1] + va[2] + va[3];
  float qa = va[0]*va[0] + va[1]*va[1] + va[2]*va[2] + va[3]*va[3];
  float sc = 0.f, qc = 0.f;
#pragma unroll
  for (int j = 0; j < 8; ++j) { sc += vc[j]; qc += vc[j] * vc[j]; }
#pragma unroll
  for (int off = 32; off >= 1; off >>= 1) {
    sa += __shfl_xor(sa, off); qa += __shfl_xor(qa, off);
    sc += __shfl_xor(sc, off); qc += __shfl_xor(qc, off);
  }
  const float ma = sa * (1.f / 256.f);
  const float ra = rsqrtf(qa * (1.f / 256.f) - ma * ma + EPS);
  const float mc = sc * (1.f / 512.f);
  const float rc = rsqrtf(qc * (1.f / 512.f) - mc * mc + EPS);
  {
    int c = t * 4;
    *(ushort4*)&outa[(size_t)row * 256 + c] = make_ushort4(
        f2bf((va[0] - ma) * ra * ga[c + 0] + ba[c + 0]),
        f2bf((va[1] - ma) * ra * ga[c + 1] + ba[c + 1]),
        f2bf((va[2] - ma) * ra * ga[c + 2] + ba[c + 2]),
        f2bf((va[3] - ma) * ra * ga[c + 3] + ba[c + 3]));
  }
#pragma unroll
  for (int half = 0; half < 2; ++half) {
    int c = t * 8 + half * 4;
    *(ushort4*)&outc[(size_t)row * 512 + c] = make_ushort4(
        f2bf((vc[half * 4 + 0] - mc) * rc * gc[c + 0] + bc[c + 0]),
        f2bf((vc[half * 4 + 1] - mc) * rc * gc[c + 1] + bc[c + 1]),
        f2bf((vc[half * 4 + 2] - mc) * rc * gc[c + 2] + bc[c + 2]),
        f2bf((vc[half * 4 + 3] - mc) * rc * gc[c + 3] + bc[c + 3]));
  }
}

// ---------------------------------------------------------------------------
// Depthwise 3x3 + BN1 + GELU, bf16 LDS tile, vectorized staging.
// ---------------------------------------------------------------------------
__global__ __launch_bounds__(256) void dwconv_bn_gelu(
    const unsigned short* __restrict__ xin, const float* __restrict__ wgt9,
    const float* __restrict__ dwb, const float* __restrict__ g1,
    const float* __restrict__ b1, const float* __restrict__ m1,
    const float* __restrict__ v1, unsigned short* __restrict__ outp,
    float* __restrict__ ci_part) {
  __shared__ unsigned short tile[100 * 128];
  __shared__ float psum[8 * 128];
  const int b_ = blockIdx.x;
  const int b = b_ / 784, win = b_ % 784;
  const int wi = win / 28, wj = win % 28;
  const int h0 = wi * 8 - 1, w0 = wj * 8 - 1;
  const int tid = threadIdx.x;
  const int c4 = (tid & 31) * 4;
  const int pg = tid >> 5;
  for (int chunk = 0; chunk < 4; ++chunk) {
    const int c0 = chunk * 128;
    __syncthreads();
#pragma unroll
    for (int it = 0; it < 7; ++it) {
      int idx = it * 256 + tid;
      if (idx < 1600) {
        int p = idx >> 4;
        int ch8 = (idx & 15) * 8;
        int ph = h0 + p / 10, pw = w0 + p % 10;
        uint4 val = {0u, 0u, 0u, 0u};
        if (ph >= 0 && ph < 224 && pw >= 0 && pw < 224) {
          int bs = b * 784 + (ph >> 3) * 28 + (pw >> 3);
          int n = ((ph & 7) << 3) | (pw & 7);
          val = *(const uint4*)&xin[(size_t)(bs * 64 + n) * 512 + c0 + ch8];
        }
        *(uint4*)&tile[p * 128 + ch8] = val;
      }
    }
    __syncthreads();
    float wreg[9][4];
    float scale[4], shift[4], bias0[4];
#pragma unroll
    for (int j = 0; j < 4; ++j) {
      int cc = c0 + c4 + j;
#pragma unroll
      for (int k = 0; k < 9; ++k) wreg[k][j] = wgt9[cc * 9 + k];
      scale[j] = g1[cc] * rsqrtf(v1[cc] + EPS);
      shift[j] = b1[cc] - m1[cc] * scale[j];
      bias0[j] = dwb[cc];
    }
    float cs0 = 0.f, cs1 = 0.f, cs2 = 0.f, cs3 = 0.f;
    for (int q = 0; q < 8; ++q) {
      const int qq = pg * 8 + q;
      const int r = qq >> 3, cc_ = qq & 7;
      float a0 = bias0[0], a1 = bias0[1], a2 = bias0[2], a3 = bias0[3];
#pragma unroll
      for (int dr = 0; dr < 3; ++dr)
#pragma unroll
        for (int dc = 0; dc < 3; ++dc) {
          ushort4 u = *(const ushort4*)&tile[((r + dr) * 10 + cc_ + dc) * 128 + c4];
          const int k = dr * 3 + dc;
          a0 += bf2f(u.x) * wreg[k][0];
          a1 += bf2f(u.y) * wreg[k][1];
          a2 += bf2f(u.z) * wreg[k][2];
          a3 += bf2f(u.w) * wreg[k][3];
        }
      float g0 = gelu_exact(a0 * scale[0] + shift[0]);
      float g1v = gelu_exact(a1 * scale[1] + shift[1]);
      float g2v = gelu_exact(a2 * scale[2] + shift[2]);
      float g3v = gelu_exact(a3 * scale[3] + shift[3]);
      cs0 += g0; cs1 += g1v; cs2 += g2v; cs3 += g3v;
      *(ushort4*)&outp[(size_t)(b_ * 64 + qq) * 512 + c0 + c4] =
          make_ushort4(f2bf(g0), f2bf(g1v), f2bf(g2v), f2bf(g3v));
    }
    *(float4*)&psum[pg * 128 + c4] = make_float4(cs0, cs1, cs2, cs3);
    __syncthreads();
    if (tid < 128) {
      float s = 0.f;
#pragma unroll
      for (int g = 0; g < 8; ++g) s += psum[g * 128 + tid];
      ci_part[(size_t)b_ * 512 + c0 + tid] = s;
    }
  }
}

__global__ __launch_bounds__(512) void ci_reduce(const float* __restrict__ ci_part,
                                                 float* __restrict__ ci_mean) {
  const int b = blockIdx.x, c = threadIdx.x;
  float s = 0.f;
  for (int w = 0; w < 784; ++w) s += ci_part[(size_t)(b * 784 + w) * 512 + c];
  ci_mean[b * 512 + c] = s * (1.f / 50176.f);
}

__global__ __launch_bounds__(512) void ci_gate(
    const float* __restrict__ ci_mean, const float* __restrict__ w1,
    const float* __restrict__ bi1, const float* __restrict__ g2,
    const float* __restrict__ b2, const float* __restrict__ m2,
    const float* __restrict__ v2, const float* __restrict__ w2,
    const float* __restrict__ bi2, float* __restrict__ gate) {
  __shared__ float cm[1024];
  __shared__ float c1[128];
  const int t = threadIdx.x;
  cm[t] = ci_mean[t];
  cm[t + 512] = ci_mean[t + 512];
  __syncthreads();
  if (t < 128) {
    int b = t >> 6, j = t & 63;
    float acc = bi1[j];
    for (int c = 0; c < 512; ++c) acc += cm[b * 512 + c] * w1[c * 64 + j];
    float sc = g2[j] * rsqrtf(v2[j] + EPS);
    c1[t] = gelu_exact((acc - m2[j]) * sc + b2[j]);
  }
  __syncthreads();
  {
    int b = t >> 8, o = t & 255;
    float acc = bi2[o];
#pragma unroll
    for (int j = 0; j < 64; ++j) acc += c1[b * 64 + j] * w2[j * 256 + o];
    gate[b * 256 + o] = 1.f / (1.f + expf(-acc));
  }
}

// ---------------------------------------------------------------------------
// Fused attention + si gate + BN3 + LN-out + concat (round-13 proven v3).
// ---------------------------------------------------------------------------
__global__ __launch_bounds__(256) void attn_si(
    const unsigned short* __restrict__ qkv,   // (M,768) bf16
    const unsigned short* __restrict__ xpj,   // (M,256) bf16
    const float* __restrict__ gate, const float* __restrict__ biasf,
    const unsigned short* __restrict__ siw1t, // (64,256) bf16 = si_w1^T
    const float* __restrict__ bi1, const float* __restrict__ g4,
    const float* __restrict__ b4v, const float* __restrict__ m4,
    const float* __restrict__ v4, const float* __restrict__ w2,
    const float* __restrict__ bi2,
    const float* __restrict__ g3, const float* __restrict__ b3v,
    const float* __restrict__ m3, const float* __restrict__ v3,
    const float* __restrict__ glno, const float* __restrict__ blno,
    unsigned short* __restrict__ outc) {      // (M,512) bf16
  __shared__ unsigned short smem[17920];  // 35840 B union
  __shared__ float sig[64];
  const int w = blockIdx.x;
  const int b = w / 784;
  const int tid = threadIdx.x, lane = tid & 63, wave = tid >> 6;
  unsigned short* vT = smem + wave * 4480;   // [32][68]
  unsigned short* ph = vT + 2176;            // [64][36]
  const int l15 = lane & 15, l4 = lane >> 4;
  const float scale = 0.17677669529663687f;
  f32x4 o0[4][2], o1[4][2];
#pragma unroll
  for (int hh = 0; hh < 2; ++hh) {
    const int h = wave * 2 + hh;
    {
      const float* gh = &gate[b * 256 + h * 32];
      const size_t vbase = ((size_t)w * 64 + lane) * 768 + 512 + h * 32;
#pragma unroll
      for (int c = 0; c < 4; ++c) {
        uint4 vv = *(const uint4*)&qkv[vbase + c * 8];
        float4 gA = *(const float4*)&gh[c * 8];
        float4 gB = *(const float4*)&gh[c * 8 + 4];
        unsigned vw[4] = {vv.x, vv.y, vv.z, vv.w};
        float gg[8] = {gA.x, gA.y, gA.z, gA.w, gB.x, gB.y, gB.z, gB.w};
#pragma unroll
        for (int j = 0; j < 4; ++j) {
          int d = c * 8 + j * 2;
          vT[(d + 0) * 68 + lane] = f2bf(__uint_as_float(vw[j] << 16) * gg[j * 2]);
          vT[(d + 1) * 68 + lane] =
              f2bf(__uint_as_float(vw[j] & 0xffff0000u) * gg[j * 2 + 1]);
        }
      }
    }
    bf16x8 kf[4], qf[4];
    const size_t qkbase = (size_t)w * 64 * 768 + h * 32 + l4 * 8;
#pragma unroll
    for (int t = 0; t < 4; ++t) {
      kf[t] = *(const bf16x8*)&qkv[qkbase + (size_t)(t * 16 + l15) * 768 + 256];
      qf[t] = *(const bf16x8*)&qkv[qkbase + (size_t)(t * 16 + l15) * 768];
    }
    f32x4 s[4][4];
#pragma unroll
    for (int mt = 0; mt < 4; ++mt)
#pragma unroll
      for (int nt = 0; nt < 4; ++nt) s[mt][nt] = (f32x4){0.f, 0.f, 0.f, 0.f};
#pragma unroll
    for (int mt = 0; mt < 4; ++mt)
#pragma unroll
      for (int nt = 0; nt < 4; ++nt)
        s[mt][nt] = __builtin_amdgcn_mfma_f32_16x16x32_bf16(kf[mt], qf[nt],
                                                            s[mt][nt], 0, 0, 0);
    float inv_s[4];
#pragma unroll
    for (int nt = 0; nt < 4; ++nt) {
      float mx = -1e30f;
#pragma unroll
      for (int mt = 0; mt < 4; ++mt) {
        float4 b4 = *(const float4*)&biasf[(h * 64 + nt * 16 + l15) * 64 +
                                           mt * 16 + l4 * 4];
        s[mt][nt][0] = s[mt][nt][0] * scale + b4.x;
        s[mt][nt][1] = s[mt][nt][1] * scale + b4.y;
        s[mt][nt][2] = s[mt][nt][2] * scale + b4.z;
        s[mt][nt][3] = s[mt][nt][3] * scale + b4.w;
#pragma unroll
        for (int r = 0; r < 4; ++r) mx = fmaxf(mx, s[mt][nt][r]);
      }
      mx = fmaxf(mx, __shfl_xor(mx, 16));
      mx = fmaxf(mx, __shfl_xor(mx, 32));
      float sum = 0.f;
#pragma unroll
      for (int mt = 0; mt < 4; ++mt)
#pragma unroll
        for (int r = 0; r < 4; ++r) {
          float e = __expf(s[mt][nt][r] - mx);
          s[mt][nt][r] = e;
          sum += e;
        }
      sum += __shfl_xor(sum, 16);
      sum += __shfl_xor(sum, 32);
      inv_s[nt] = 1.f / sum;
    }
#pragma unroll
    for (int i = 0; i < 4; ++i)
#pragma unroll
      for (int dt = 0; dt < 2; ++dt)
        (hh ? o1 : o0)[i][dt] = (f32x4){0.f, 0.f, 0.f, 0.f};
#pragma unroll
    for (int ks = 0; ks < 2; ++ks) {
#pragma unroll
      for (int nt = 0; nt < 4; ++nt)
#pragma unroll
        for (int mh = 0; mh < 2; ++mh) {
          const int mt = 2 * ks + mh;
          ushort4 pk = make_ushort4(f2bf(s[mt][nt][0] * inv_s[nt]),
                                    f2bf(s[mt][nt][1] * inv_s[nt]),
                                    f2bf(s[mt][nt][2] * inv_s[nt]),
                                    f2bf(s[mt][nt][3] * inv_s[nt]));
          *(ushort4*)&ph[(nt * 16 + l15) * 36 + mh * 16 + l4 * 4] = pk;
        }
      bf16x8 pa[4], vf[2];
#pragma unroll
      for (int i = 0; i < 4; ++i) {
        const unsigned short* pp = &ph[(i * 16 + l15) * 36 + l4 * 8];
        union { bf16x8 v; ushort4 u[2]; } tmp;
        tmp.u[0] = *(const ushort4*)pp;
        tmp.u[1] = *(const ushort4*)(pp + 4);
        pa[i] = tmp.v;
      }
#pragma unroll
      for (int dt = 0; dt < 2; ++dt) {
        const unsigned short* vp = &vT[(dt * 16 + l15) * 68 + ks * 32 + l4 * 8];
        union { bf16x8 v; ushort4 u[2]; } tmp;
        tmp.u[0] = *(const ushort4*)vp;
        tmp.u[1] = *(const ushort4*)(vp + 4);
        vf[dt] = tmp.v;
      }
#pragma unroll
      for (int i = 0; i < 4; ++i)
#pragma unroll
        for (int dt = 0; dt < 2; ++dt)
          (hh ? o1 : o0)[i][dt] = __builtin_amdgcn_mfma_f32_16x16x32_bf16(
              pa[i], vf[dt], (hh ? o1 : o0)[i][dt], 0, 0, 0);
    }
  }
  __syncthreads();
  unsigned short* xattO = smem;
#pragma unroll
  for (int hh = 0; hh < 2; ++hh) {
    const int h = wave * 2 + hh;
#pragma unroll
    for (int i = 0; i < 4; ++i)
#pragma unroll
      for (int dt = 0; dt < 2; ++dt)
#pragma unroll
        for (int r = 0; r < 4; ++r)
          xattO[(i * 16 + l4 * 4 + r) * 264 + h * 32 + dt * 16 + l15] =
              f2bf((hh ? o1 : o0)[i][dt][r]);
  }
  __syncthreads();
  {
    f32x4 a4[4];
#pragma unroll
    for (int n = 0; n < 4; ++n) a4[n] = (f32x4){0.f, 0.f, 0.f, 0.f};
#pragma unroll
    for (int ks = 0; ks < 8; ++ks) {
      bf16x8 af = *(const bf16x8*)&xattO[(wave * 16 + l15) * 264 + ks * 32 + l4 * 8];
#pragma unroll
      for (int n = 0; n < 4; ++n) {
        bf16x8 bfr = *(const bf16x8*)&siw1t[(n * 16 + l15) * 256 + ks * 32 + l4 * 8];
        a4[n] = __builtin_amdgcn_mfma_f32_16x16x32_bf16(af, bfr, a4[n], 0, 0, 0);
      }
    }
    float part[4] = {0.f, 0.f, 0.f, 0.f};
#pragma unroll
    for (int n = 0; n < 4; ++n) {
      const int j = n * 16 + l15;
      const float sc4 = g4[j] * rsqrtf(v4[j] + EPS);
      const float m4j = m4[j], b4j = b4v[j], bij = bi1[j], w2j = w2[j];
#pragma unroll
      for (int r = 0; r < 4; ++r)
        part[r] += gelu_exact((a4[n][r] + bij - m4j) * sc4 + b4j) * w2j;
    }
#pragma unroll
    for (int r = 0; r < 4; ++r) {
      part[r] += __shfl_xor(part[r], 1);
      part[r] += __shfl_xor(part[r], 2);
      part[r] += __shfl_xor(part[r], 4);
      part[r] += __shfl_xor(part[r], 8);
    }
    if (l15 == 0) {
      const float b2v = bi2[0];
#pragma unroll
      for (int r = 0; r < 4; ++r)
        sig[wave * 16 + l4 * 4 + r] = 1.f / (1.f + expf(-(part[r] + b2v)));
    }
  }
  __syncthreads();
  {
    const int p = tid >> 2, l = tid & 3;
    float s = 0.f, sq = 0.f;
#pragma unroll
    for (int k = 0; k < 16; ++k) {
      ushort4 u = *(const ushort4*)&xattO[p * 264 + l * 4 + k * 16];
      float x0 = bf2f(u.x), x1 = bf2f(u.y), x2 = bf2f(u.z), x3 = bf2f(u.w);
      s += x0 + x1 + x2 + x3;
      sq += x0 * x0 + x1 * x1 + x2 * x2 + x3 * x3;
    }
    s += __shfl_xor(s, 1);  sq += __shfl_xor(sq, 1);
    s += __shfl_xor(s, 2);  sq += __shfl_xor(sq, 2);
    const float mean = s * (1.f / 256.f);
    const float var = sq * (1.f / 256.f) - mean * mean;
    const float rstd = rsqrtf(var + EPS);
    const size_t orow = ((size_t)w * 64 + p) * 512;
    const float sg = sig[p];
#pragma unroll
    for (int k = 0; k < 16; ++k) {
      const int c = l * 4 + k * 16;
      ushort4 u = *(const ushort4*)&xattO[p * 264 + c];
      *(ushort4*)&outc[orow + c] = make_ushort4(
          f2bf((bf2f(u.x) - mean) * rstd * glno[c + 0] + blno[c + 0]),
          f2bf((bf2f(u.y) - mean) * rstd * glno[c + 1] + blno[c + 1]),
          f2bf((bf2f(u.z) - mean) * rstd * glno[c + 2] + blno[c + 2]),
          f2bf((bf2f(u.w) - mean) * rstd * glno[c + 3] + blno[c + 3]));
      ushort4 pu = *(const ushort4*)&xpj[((size_t)w * 64 + p) * 256 + c];
      float sc0 = g3[c + 0] * rsqrtf(v3[c + 0] + EPS);
      float sc1 = g3[c + 1] * rsqrtf(v3[c + 1] + EPS);
      float sc2 = g3[c + 2] * rsqrtf(v3[c + 2] + EPS);
      float sc3 = g3[c + 3] * rsqrtf(v3[c + 3] + EPS);
      *(ushort4*)&outc[orow + 256 + c] = make_ushort4(
          f2bf(sg * bf2f(pu.x) * sc0 + (b3v[c + 0] - m3[c + 0] * sc0)),
          f2bf(sg * bf2f(pu.y) * sc1 + (b3v[c + 1] - m3[c + 1] * sc1)),
          f2bf(sg * bf2f(pu.z) * sc2 + (b3v[c + 2] - m3[c + 2] * sc2)),
          f2bf(sg * bf2f(pu.w) * sc3 + (b3v[c + 3] - m3[c + 3] * sc3)));
    }
  }
}

// ---------------------------------------------------------------------------
extern "C" void kernel_launch(void* const* d_in, const int* in_sizes, int n_in,
                              void* d_out, int out_size, void* d_ws, size_t ws_size,
                              hipStream_t stream) {
  const float* x     = (const float*)d_in[0];
  const float* w_pa  = (const float*)d_in[1];
  const float* b_pa  = (const float*)d_in[2];
  const float* g_lna = (const float*)d_in[3];
  const float* b_lna = (const float*)d_in[4];
  const float* w_pc  = (const float*)d_in[5];
  const float* b_pc  = (const float*)d_in[6];
  const float* g_lnc = (const float*)d_in[7];
  const float* b_lnc = (const float*)d_in[8];
  const float* dw_w  = (const float*)d_in[9];
  const float* dw_b  = (const float*)d_in[10];
  const float* g_bn1 = (const float*)d_in[11];
  const float* b_bn1 = (const float*)d_in[12];
  const float* m_bn1 = (const float*)d_in[13];
  const float* v_bn1 = (const float*)d_in[14];
  const float* ci_w1 = (const float*)d_in[15];
  const float* ci_b1 = (const float*)d_in[16];
  const float* g_bn2 = (const float*)d_in[17];
  const float* b_bn2 = (const float*)d_in[18];
  const float* m_bn2 = (const float*)d_in[19];
  const float* v_bn2 = (const float*)d_in[20];
  const float* ci_w2 = (const float*)d_in[21];
  const float* ci_b2 = (const float*)d_in[22];
  const float* pj_w  = (const float*)d_in[23];
  const float* pj_b  = (const float*)d_in[24];
  const float* g_bn3 = (const float*)d_in[25];
  const float* b_bn3 = (const float*)d_in[26];
  const float* m_bn3 = (const float*)d_in[27];
  const float* v_bn3 = (const float*)d_in[28];
  const float* w_qkv = (const float*)d_in[29];
  const float* b_qkv = (const float*)d_in[30];
  const float* si_w1 = (const float*)d_in[31];
  const float* si_b1 = (const float*)d_in[32];
  const float* g_bn4 = (const float*)d_in[33];
  const float* b_bn4 = (const float*)d_in[34];
  const float* m_bn4 = (const float*)d_in[35];
  const float* v_bn4 = (const float*)d_in[36];
  const float* si_w2 = (const float*)d_in[37];
  const float* si_b2 = (const float*)d_in[38];
  const float* g_lno = (const float*)d_in[39];
  const float* b_lno = (const float*)d_in[40];
  const float* w_out = (const float*)d_in[41];
  const float* b_out = (const float*)d_in[42];
  const float* rpb   = (const float*)d_in[43];
  const int*   rel   = (const int*)d_in[44];

  char* ws = (char*)d_ws;
  unsigned short* G12BF = (unsigned short*)(ws + 0);            // (M,768)
  unsigned short* QKVBF = (unsigned short*)(ws + 0);            // (M,768)
  unsigned short* A1BF  = (unsigned short*)(ws + 154140672ull); // (M,256)
  unsigned short* C1BF  = (unsigned short*)(ws + 205520896ull); // (M,512)
  unsigned short* CAT   = (unsigned short*)(ws + 205520896ull); // (M,512)
  unsigned short* XBF   = (unsigned short*)(ws + 308281344ull); // (M,512)
  unsigned short* CVBF  = (unsigned short*)(ws + 308281344ull); // (M,512)
  unsigned short* PJBF  = (unsigned short*)(ws + 411041792ull); // (M,256)
  float*          CIP   = (float*)(ws + 462422016ull);          // (1568,512)
  float*          CIM   = (float*)(ws + 465633280ull);          // (2,512)
  float*          GATE  = (float*)(ws + 465637376ull);          // (2,256)
  float*          B12   = (float*)(ws + 465639424ull);          // (768)
  float*          BIASF = (float*)(ws + 465642496ull);          // (8,64,64)
  unsigned short* WT    = (unsigned short*)(ws + 465773568ull);
  unsigned short* WpaT  = WT + 0;        // (256,512)
  unsigned short* WpcT  = WT + 131072;   // (512,512)
  unsigned short* PjT   = WT + 393216;   // (256,512)
  unsigned short* QkvT  = WT + 524288;   // (768,256)
  unsigned short* OutT  = WT + 720896;   // (512,512)
  unsigned short* SiT   = WT + 983040;   // (64,256)

  const int M = MROWS;
  dim3 b256(256), b512(512);

  // 0) fused prep + x->bf16
  prep_all<<<3923, b256, 0, stream>>>(w_pa, w_pc, pj_w, w_qkv, w_out, si_w1,
                                      b_pa, b_pc, rpb, rel,
                                      WpaT, WpcT, PjT, QkvT, OutT, SiT,
                                      B12, BIASF);
  cvt_bf16<<<(M * 512 / 8 + 255) / 256, b256, 0, stream>>>(x, XBF, M * 512 / 8);

  // 1+2) fused input GEMM: [x@w_pa | x@w_pc] -> G12BF (M,768)
  gemm256<true><<<dim3(3, M / 256), dim3(512), 0, stream>>>(XBF, WpaT, B12, G12BF,
                                                            M, 768, 512);
  ln_dual<<<M / 4, b256, 0, stream>>>(G12BF, A1BF, C1BF, g_lna, b_lna, g_lnc, b_lnc);

  // 3) depthwise conv + BN1 + GELU + channel sums (XBF dead -> CVBF)
  dwconv_bn_gelu<<<NWIN, b256, 0, stream>>>(C1BF, dw_w, dw_b, g_bn1, b_bn1, m_bn1,
                                            v_bn1, CVBF, CIP);
  ci_reduce<<<2, b512, 0, stream>>>(CIP, CIM);
  ci_gate<<<1, b512, 0, stream>>>(CIM, ci_w1, ci_b1, g_bn2, b_bn2, m_bn2, v_bn2,
                                  ci_w2, ci_b2, GATE);

  // 4) pj GEMM (bf16 out)
  gemm256<true><<<dim3(1, M / 256), dim3(512), 0, stream>>>(CVBF, PjT, pj_b, PJBF,
                                                            M, 256, 512);

  // 5) qkv GEMM (bf16 out; G12BF dead -> QKVBF)
  gemm256<true><<<dim3(3, M / 256), dim3(512), 0, stream>>>(A1BF, QkvT, b_qkv, QKVBF,
                                                            M, 768, 256);

  // 6) fused attention + si gate + BN3 + LN + concat (C1BF dead -> CAT)
  attn_si<<<NWIN, b256, 0, stream>>>(QKVBF, PJBF, GATE, BIASF, SiT,
                                     si_b1, g_bn4, b_bn4, m_bn4, v_bn4,
                                     si_w2, si_b2,
                                     g_bn3, b_bn3, m_bn3, v_bn3,
                                     g_lno, b_lno, CAT);

  // 7) final GEMM -> d_out (f32)
  gemm256<false><<<dim3(2, M / 256), dim3(512), 0, stream>>>(CAT, OutT, b_out,
                                                             (float*)d_out, M, 512, 512);
}

// Round 17
// 815.616 us; speedup vs baseline: 1.0638x; 1.0010x over previous
//
#include <hip/hip_runtime.h>
#include <math.h>

#define EPS 1e-5f
#define MROWS 100352        // B_ * N = 1568 * 64
#define NWIN  1568

typedef __attribute__((ext_vector_type(8))) short bf16x8;
typedef __attribute__((ext_vector_type(4))) float f32x4;

__device__ __forceinline__ unsigned short f2bf(float f) {
  unsigned u = __float_as_uint(f);
  u += 0x7fffu + ((u >> 16) & 1u);
  return (unsigned short)(u >> 16);
}
__device__ __forceinline__ float bf2f(unsigned short s) {
  return __uint_as_float(((unsigned)s) << 16);
}
__device__ __forceinline__ float gelu_exact(float x) {
  return 0.5f * x * (1.f + erff(x * 0.70710678118654752f));
}

#define GLOAD16(gp, lp)                                              \
  __builtin_amdgcn_global_load_lds(                                  \
      (const __attribute__((address_space(1))) void*)(gp),           \
      (__attribute__((address_space(3))) void*)(lp), 16, 0, 0)

// ---------------------------------------------------------------------------
// 256x256-tile 8-phase bf16 MFMA GEMM (proven BK=64 round-7 version).
// ---------------------------------------------------------------------------
__device__ __forceinline__ void stage_half256(
    const unsigned short* __restrict__ base, int r0, int K, int kk,
    unsigned short* lds, int ldsbase, int tid) {
#pragma unroll
  for (int inst = 0; inst < 2; ++inst) {
    int r = inst * 64 + (tid >> 3);
    int cb = ((tid & 7) << 4) ^ ((r & 7) << 4);
    const unsigned short* src = base + (size_t)(r0 + r) * K + kk + (cb >> 1);
    GLOAD16(src, &lds[ldsbase + inst * 4096 + tid * 8]);
  }
}

__device__ __forceinline__ bf16x8 frag_read256(const unsigned short* lds,
                                               int tilebase, int r_t, int cbyte) {
  int off = r_t * 128 + cbyte;
  int phys = off ^ ((r_t & 7) << 4);
  return *(const bf16x8*)&lds[tilebase + (phys >> 1)];
}

template <bool OUTBF>
__global__ __launch_bounds__(512) void gemm256(
    const unsigned short* __restrict__ A, const unsigned short* __restrict__ Bt,
    const float* __restrict__ bias, void* __restrict__ Cout,
    int M, int N, int K) {
  __shared__ unsigned short lds[65536];
  const int tid = threadIdx.x;
  const int lane = tid & 63, wave = tid >> 6;
  const int wr = wave >> 2, wcn = wave & 3;
  int bx, by;
  {
    const int nwg = gridDim.x * gridDim.y;
    int n = blockIdx.y * gridDim.x + blockIdx.x;
    int w = ((nwg & 7) == 0) ? ((n & 7) * (nwg >> 3) + (n >> 3)) : n;
    by = w / gridDim.x;
    bx = w - by * gridDim.x;
  }
  const int row0 = by * 256, col0 = bx * 256;
  const int rl = lane & 15, qd = lane >> 4;
  f32x4 acc[8][4];
#pragma unroll
  for (int m = 0; m < 8; ++m)
#pragma unroll
    for (int n = 0; n < 4; ++n) acc[m][n] = (f32x4){0.f, 0.f, 0.f, 0.f};

  const int KT = K >> 6;
  stage_half256(A, row0, K, 0, lds, 0, tid);
  stage_half256(A, row0 + 128, K, 0, lds, 8192, tid);
  stage_half256(Bt, col0, K, 0, lds, 16384, tid);
  stage_half256(Bt, col0 + 128, K, 0, lds, 24576, tid);

  for (int kt = 0; kt < KT; ++kt) {
    const int b = kt & 1;
    const int abase = b * 32768, bbase = b * 32768 + 16384;
    const int nb = b ^ 1;
    const int kkn = (kt + 1) << 6;
    const bool last = (kt == KT - 1);
    bf16x8 bfr[4][2];
#pragma unroll
    for (int p = 0; p < 4; ++p) {
      if (!last) {
        if (p == 0)      stage_half256(A, row0, K, kkn, lds, nb * 32768, tid);
        else if (p == 1) stage_half256(A, row0 + 128, K, kkn, lds, nb * 32768 + 8192, tid);
        else if (p == 2) stage_half256(Bt, col0, K, kkn, lds, nb * 32768 + 16384, tid);
        else             stage_half256(Bt, col0 + 128, K, kkn, lds, nb * 32768 + 24576, tid);
      }
      if (p == 0) {
        if (!last) asm volatile("s_waitcnt vmcnt(2)" ::: "memory");
        else       asm volatile("s_waitcnt vmcnt(0)" ::: "memory");
      }
      __builtin_amdgcn_s_barrier();
      __builtin_amdgcn_sched_barrier(0);
      if (p == 0) {
#pragma unroll
        for (int n = 0; n < 4; ++n)
#pragma unroll
          for (int ks = 0; ks < 2; ++ks)
            bfr[n][ks] = frag_read256(lds, bbase, wcn * 64 + n * 16 + rl,
                                      ks * 64 + qd * 16);
      }
      bf16x8 af[2][2];
#pragma unroll
      for (int i = 0; i < 2; ++i)
#pragma unroll
        for (int ks = 0; ks < 2; ++ks)
          af[i][ks] = frag_read256(lds, abase, wr * 128 + (2 * p + i) * 16 + rl,
                                   ks * 64 + qd * 16);
      __builtin_amdgcn_s_setprio(1);
#pragma unroll
      for (int i = 0; i < 2; ++i)
#pragma unroll
        for (int n = 0; n < 4; ++n)
#pragma unroll
          for (int ks = 0; ks < 2; ++ks)
            acc[2 * p + i][n] = __builtin_amdgcn_mfma_f32_16x16x32_bf16(
                af[i][ks], bfr[n][ks], acc[2 * p + i][n], 0, 0, 0);
      __builtin_amdgcn_s_setprio(0);
      __builtin_amdgcn_s_barrier();
    }
  }
  const int crow = qd * 4, ccol = rl;
#pragma unroll
  for (int n = 0; n < 4; ++n) {
    const int gc = col0 + wcn * 64 + n * 16 + ccol;
    const float bz = bias[gc];
#pragma unroll
    for (int m = 0; m < 8; ++m) {
      const int gr0 = row0 + wr * 128 + m * 16 + crow;
#pragma unroll
      for (int r = 0; r < 4; ++r) {
        float val = acc[m][n][r] + bz;
        if constexpr (OUTBF)
          ((unsigned short*)Cout)[(size_t)(gr0 + r) * N + gc] = f2bf(val);
        else
          ((float*)Cout)[(size_t)(gr0 + r) * N + gc] = val;
      }
    }
  }
}

// ---------------------------------------------------------------------------
// One fused prep kernel: weight transposes + bias pack + rel-pos bias table.
// ---------------------------------------------------------------------------
__device__ __forceinline__ void wtc(const float* in, unsigned short* out,
                                    int K, int N, int i) {
  if (i < K * N) {
    int n = i / K, k = i - n * K;
    out[i] = f2bf(in[(size_t)k * N + n]);
  }
}

__global__ __launch_bounds__(256) void prep_all(
    const float* __restrict__ w_pa, const float* __restrict__ w_pc,
    const float* __restrict__ pj_w, const float* __restrict__ w_qkv,
    const float* __restrict__ w_out, const float* __restrict__ si_w1,
    const float* __restrict__ b_pa, const float* __restrict__ b_pc,
    const float* __restrict__ rpb, const int* __restrict__ rel,
    unsigned short* __restrict__ WpaT, unsigned short* __restrict__ WpcT,
    unsigned short* __restrict__ PjT, unsigned short* __restrict__ QkvT,
    unsigned short* __restrict__ OutT, unsigned short* __restrict__ SiT,
    float* __restrict__ B12, float* __restrict__ biasf) {
  const int blk = blockIdx.x, t = threadIdx.x;
  if (blk < 512)        wtc(w_pa, WpaT, 512, 256, blk * 256 + t);
  else if (blk < 1536)  wtc(w_pc, WpcT, 512, 512, (blk - 512) * 256 + t);
  else if (blk < 2048)  wtc(pj_w, PjT, 512, 256, (blk - 1536) * 256 + t);
  else if (blk < 2816)  wtc(w_qkv, QkvT, 256, 768, (blk - 2048) * 256 + t);
  else if (blk < 3840)  wtc(w_out, OutT, 512, 512, (blk - 2816) * 256 + t);
  else if (blk < 3904)  wtc(si_w1, SiT, 256, 64, (blk - 3840) * 256 + t);
  else if (blk == 3904) { B12[t] = b_pa[t]; }
  else if (blk < 3907)  { int i = (blk - 3905) * 256 + t; if (i < 512) B12[256 + i] = b_pc[i]; }
  else {
    int i = (blk - 3907) * 256 + t;
    if (i < 4096) {
      int r = rel[i];
#pragma unroll
      for (int h = 0; h < 8; ++h) biasf[h * 4096 + i] = rpb[r * 8 + h];
    }
  }
}

// x (f32) -> bf16, 8 elems/thread.
__global__ __launch_bounds__(256) void cvt_bf16(const float* __restrict__ in,
                                                unsigned short* __restrict__ out,
                                                int n8) {
  int i = blockIdx.x * 256 + threadIdx.x;
  if (i >= n8) return;
  float4 a = ((const float4*)in)[i * 2];
  float4 b = ((const float4*)in)[i * 2 + 1];
  ((ushort4*)out)[i * 2] = make_ushort4(f2bf(a.x), f2bf(a.y), f2bf(a.z), f2bf(a.w));
  ((ushort4*)out)[i * 2 + 1] = make_ushort4(f2bf(b.x), f2bf(b.y), f2bf(b.z), f2bf(b.w));
}

// ---------------------------------------------------------------------------
// Dual LayerNorm: one read of (M,768) row -> LN-256 out + LN-512 out.
// ---------------------------------------------------------------------------
__global__ __launch_bounds__(256) void ln_dual(
    const unsigned short* __restrict__ in,
    unsigned short* __restrict__ outa, unsigned short* __restrict__ outc,
    const float* __restrict__ ga, const float* __restrict__ ba,
    const float* __restrict__ gc, const float* __restrict__ bc) {
  const int row = blockIdx.x * 4 + (threadIdx.x >> 6);
  const int t = threadIdx.x & 63;
  const size_t ibase = (size_t)row * 768;
  float va[4], vc[8];
  {
    ushort4 u = *(const ushort4*)&in[ibase + t * 4];
    va[0] = bf2f(u.x); va[1] = bf2f(u.y); va[2] = bf2f(u.z); va[3] = bf2f(u.w);
    ushort4 u0 = *(const ushort4*)&in[ibase + 256 + t * 8];
    ushort4 u1 = *(const ushort4*)&in[ibase + 256 + t * 8 + 4];
    vc[0] = bf2f(u0.x); vc[1] = bf2f(u0.y); vc[2] = bf2f(u0.z); vc[3] = bf2f(u0.w);
    vc[4] = bf2f(u1.x); vc[5] = bf2f(u1.y); vc[6] = bf2f(u1.z); vc[7] = bf2f(u1.w);
  }
  float sa = va[0] + va[1] + va[2] + va[3];
  float qa = va[0]*va[0] + va[1]*va[1] + va[2]*va[2] + va[3]*va[3];
  float sc = 0.f, qc = 0.f;
#pragma unroll
  for (int j = 0; j < 8; ++j) { sc += vc[j]; qc += vc[j] * vc[j]; }
#pragma unroll
  for (int off = 32; off >= 1; off >>= 1) {
    sa += __shfl_xor(sa, off); qa += __shfl_xor(qa, off);
    sc += __shfl_xor(sc, off); qc += __shfl_xor(qc, off);
  }
  const float ma = sa * (1.f / 256.f);
  const float ra = rsqrtf(qa * (1.f / 256.f) - ma * ma + EPS);
  const float mc = sc * (1.f / 512.f);
  const float rc = rsqrtf(qc * (1.f / 512.f) - mc * mc + EPS);
  {
    int c = t * 4;
    *(ushort4*)&outa[(size_t)row * 256 + c] = make_ushort4(
        f2bf((va[0] - ma) * ra * ga[c + 0] + ba[c + 0]),
        f2bf((va[1] - ma) * ra * ga[c + 1] + ba[c + 1]),
        f2bf((va[2] - ma) * ra * ga[c + 2] + ba[c + 2]),
        f2bf((va[3] - ma) * ra * ga[c + 3] + ba[c + 3]));
  }
#pragma unroll
  for (int half = 0; half < 2; ++half) {
    int c = t * 8 + half * 4;
    *(ushort4*)&outc[(size_t)row * 512 + c] = make_ushort4(
        f2bf((vc[half * 4 + 0] - mc) * rc * gc[c + 0] + bc[c + 0]),
        f2bf((vc[half * 4 + 1] - mc) * rc * gc[c + 1] + bc[c + 1]),
        f2bf((vc[half * 4 + 2] - mc) * rc * gc[c + 2] + bc[c + 2]),
        f2bf((vc[half * 4 + 3] - mc) * rc * gc[c + 3] + bc[c + 3]));
  }
}

// ---------------------------------------------------------------------------
// Depthwise 3x3 + BN1 + GELU, bf16 LDS tile, vectorized staging.
// ---------------------------------------------------------------------------
__global__ __launch_bounds__(256) void dwconv_bn_gelu(
    const unsigned short* __restrict__ xin, const float* __restrict__ wgt9,
    const float* __restrict__ dwb, const float* __restrict__ g1,
    const float* __restrict__ b1, const float* __restrict__ m1,
    const float* __restrict__ v1, unsigned short* __restrict__ outp,
    float* __restrict__ ci_part) {
  __shared__ unsigned short tile[100 * 128];
  __shared__ float psum[8 * 128];
  const int b_ = blockIdx.x;
  const int b = b_ / 784, win = b_ % 784;
  const int wi = win / 28, wj = win % 28;
  const int h0 = wi * 8 - 1, w0 = wj * 8 - 1;
  const int tid = threadIdx.x;
  const int c4 = (tid & 31) * 4;
  const int pg = tid >> 5;
  for (int chunk = 0; chunk < 4; ++chunk) {
    const int c0 = chunk * 128;
    __syncthreads();
#pragma unroll
    for (int it = 0; it < 7; ++it) {
      int idx = it * 256 + tid;
      if (idx < 1600) {
        int p = idx >> 4;
        int ch8 = (idx & 15) * 8;
        int ph = h0 + p / 10, pw = w0 + p % 10;
        uint4 val = {0u, 0u, 0u, 0u};
        if (ph >= 0 && ph < 224 && pw >= 0 && pw < 224) {
          int bs = b * 784 + (ph >> 3) * 28 + (pw >> 3);
          int n = ((ph & 7) << 3) | (pw & 7);
          val = *(const uint4*)&xin[(size_t)(bs * 64 + n) * 512 + c0 + ch8];
        }
        *(uint4*)&tile[p * 128 + ch8] = val;
      }
    }
    __syncthreads();
    float wreg[9][4];
    float scale[4], shift[4], bias0[4];
#pragma unroll
    for (int j = 0; j < 4; ++j) {
      int cc = c0 + c4 + j;
#pragma unroll
      for (int k = 0; k < 9; ++k) wreg[k][j] = wgt9[cc * 9 + k];
      scale[j] = g1[cc] * rsqrtf(v1[cc] + EPS);
      shift[j] = b1[cc] - m1[cc] * scale[j];
      bias0[j] = dwb[cc];
    }
    float cs0 = 0.f, cs1 = 0.f, cs2 = 0.f, cs3 = 0.f;
    for (int q = 0; q < 8; ++q) {
      const int qq = pg * 8 + q;
      const int r = qq >> 3, cc_ = qq & 7;
      float a0 = bias0[0], a1 = bias0[1], a2 = bias0[2], a3 = bias0[3];
#pragma unroll
      for (int dr = 0; dr < 3; ++dr)
#pragma unroll
        for (int dc = 0; dc < 3; ++dc) {
          ushort4 u = *(const ushort4*)&tile[((r + dr) * 10 + cc_ + dc) * 128 + c4];
          const int k = dr * 3 + dc;
          a0 += bf2f(u.x) * wreg[k][0];
          a1 += bf2f(u.y) * wreg[k][1];
          a2 += bf2f(u.z) * wreg[k][2];
          a3 += bf2f(u.w) * wreg[k][3];
        }
      float g0 = gelu_exact(a0 * scale[0] + shift[0]);
      float g1v = gelu_exact(a1 * scale[1] + shift[1]);
      float g2v = gelu_exact(a2 * scale[2] + shift[2]);
      float g3v = gelu_exact(a3 * scale[3] + shift[3]);
      cs0 += g0; cs1 += g1v; cs2 += g2v; cs3 += g3v;
      *(ushort4*)&outp[(size_t)(b_ * 64 + qq) * 512 + c0 + c4] =
          make_ushort4(f2bf(g0), f2bf(g1v), f2bf(g2v), f2bf(g3v));
    }
    *(float4*)&psum[pg * 128 + c4] = make_float4(cs0, cs1, cs2, cs3);
    __syncthreads();
    if (tid < 128) {
      float s = 0.f;
#pragma unroll
      for (int g = 0; g < 8; ++g) s += psum[g * 128 + tid];
      ci_part[(size_t)b_ * 512 + c0 + tid] = s;
    }
  }
}

__global__ __launch_bounds__(512) void ci_reduce(const float* __restrict__ ci_part,
                                                 float* __restrict__ ci_mean) {
  const int b = blockIdx.x, c = threadIdx.x;
  float s = 0.f;
  for (int w = 0; w < 784; ++w) s += ci_part[(size_t)(b * 784 + w) * 512 + c];
  ci_mean[b * 512 + c] = s * (1.f / 50176.f);
}

__global__ __launch_bounds__(512) void ci_gate(
    const float* __restrict__ ci_mean, const float* __restrict__ w1,
    const float* __restrict__ bi1, const float* __restrict__ g2,
    const float* __restrict__ b2, const float* __restrict__ m2,
    const float* __restrict__ v2, const float* __restrict__ w2,
    const float* __restrict__ bi2, float* __restrict__ gate) {
  __shared__ float cm[1024];
  __shared__ float c1[128];
  const int t = threadIdx.x;
  cm[t] = ci_mean[t];
  cm[t + 512] = ci_mean[t + 512];
  __syncthreads();
  if (t < 128) {
    int b = t >> 6, j = t & 63;
    float acc = bi1[j];
    for (int c = 0; c < 512; ++c) acc += cm[b * 512 + c] * w1[c * 64 + j];
    float sc = g2[j] * rsqrtf(v2[j] + EPS);
    c1[t] = gelu_exact((acc - m2[j]) * sc + b2[j]);
  }
  __syncthreads();
  {
    int b = t >> 8, o = t & 255;
    float acc = bi2[o];
#pragma unroll
    for (int j = 0; j < 64; ++j) acc += c1[b * 64 + j] * w2[j * 256 + o];
    gate[b * 256 + o] = 1.f / (1.f + expf(-acc));
  }
}

// ---------------------------------------------------------------------------
// Fused attention + si gate + BN3 + LN-out + concat, v3 + head-1 prefetch:
// identical math/buffers to the proven round-13 kernel; head-1's raw QKV
// (vv1/kf1/qf1) is preloaded into registers at kernel start so those global
// loads overlap head-0's full compute chain (MLP fix for the latency-bound
// profile: 280 MB moved at only 1.3 TB/s).
// ---------------------------------------------------------------------------
__global__ __launch_bounds__(256) void attn_si(
    const unsigned short* __restrict__ qkv,   // (M,768) bf16
    const unsigned short* __restrict__ xpj,   // (M,256) bf16
    const float* __restrict__ gate, const float* __restrict__ biasf,
    const unsigned short* __restrict__ siw1t, // (64,256) bf16 = si_w1^T
    const float* __restrict__ bi1, const float* __restrict__ g4,
    const float* __restrict__ b4v, const float* __restrict__ m4,
    const float* __restrict__ v4, const float* __restrict__ w2,
    const float* __restrict__ bi2,
    const float* __restrict__ g3, const float* __restrict__ b3v,
    const float* __restrict__ m3, const float* __restrict__ v3,
    const float* __restrict__ glno, const float* __restrict__ blno,
    unsigned short* __restrict__ outc) {      // (M,512) bf16
  __shared__ unsigned short smem[17920];  // 35840 B union
  __shared__ float sig[64];
  const int w = blockIdx.x;
  const int b = w / 784;
  const int tid = threadIdx.x, lane = tid & 63, wave = tid >> 6;
  unsigned short* vT = smem + wave * 4480;   // [32][68]
  unsigned short* ph = vT + 2176;            // [64][36]
  const int l15 = lane & 15, l4 = lane >> 4;
  const float scale = 0.17677669529663687f;
  f32x4 o0[4][2], o1[4][2];

  // ---- prefetch head-1's raw QKV into registers (loads fly during head 0)
  uint4 vv1[4];
  bf16x8 kf1[4], qf1[4];
  {
    const int h = wave * 2 + 1;
    const size_t vb = ((size_t)w * 64 + lane) * 768 + 512 + h * 32;
#pragma unroll
    for (int c = 0; c < 4; ++c) vv1[c] = *(const uint4*)&qkv[vb + c * 8];
    const size_t qb = (size_t)w * 64 * 768 + h * 32 + l4 * 8;
#pragma unroll
    for (int t = 0; t < 4; ++t) {
      kf1[t] = *(const bf16x8*)&qkv[qb + (size_t)(t * 16 + l15) * 768 + 256];
      qf1[t] = *(const bf16x8*)&qkv[qb + (size_t)(t * 16 + l15) * 768];
    }
  }

#pragma unroll
  for (int hh = 0; hh < 2; ++hh) {
    const int h = wave * 2 + hh;
    {
      const float* gh = &gate[b * 256 + h * 32];
      const size_t vbase = ((size_t)w * 64 + lane) * 768 + 512 + h * 32;
#pragma unroll
      for (int c = 0; c < 4; ++c) {
        uint4 vv = (hh == 0) ? *(const uint4*)&qkv[vbase + c * 8] : vv1[c];
        float4 gA = *(const float4*)&gh[c * 8];
        float4 gB = *(const float4*)&gh[c * 8 + 4];
        unsigned vw[4] = {vv.x, vv.y, vv.z, vv.w};
        float gg[8] = {gA.x, gA.y, gA.z, gA.w, gB.x, gB.y, gB.z, gB.w};
#pragma unroll
        for (int j = 0; j < 4; ++j) {
          int d = c * 8 + j * 2;
          vT[(d + 0) * 68 + lane] = f2bf(__uint_as_float(vw[j] << 16) * gg[j * 2]);
          vT[(d + 1) * 68 + lane] =
              f2bf(__uint_as_float(vw[j] & 0xffff0000u) * gg[j * 2 + 1]);
        }
      }
    }
    bf16x8 kf[4], qf[4];
    const size_t qkbase = (size_t)w * 64 * 768 + h * 32 + l4 * 8;
#pragma unroll
    for (int t = 0; t < 4; ++t) {
      if (hh == 0) {
        kf[t] = *(const bf16x8*)&qkv[qkbase + (size_t)(t * 16 + l15) * 768 + 256];
        qf[t] = *(const bf16x8*)&qkv[qkbase + (size_t)(t * 16 + l15) * 768];
      } else {
        kf[t] = kf1[t];
        qf[t] = qf1[t];
      }
    }
    f32x4 s[4][4];
#pragma unroll
    for (int mt = 0; mt < 4; ++mt)
#pragma unroll
      for (int nt = 0; nt < 4; ++nt) s[mt][nt] = (f32x4){0.f, 0.f, 0.f, 0.f};
#pragma unroll
    for (int mt = 0; mt < 4; ++mt)
#pragma unroll
      for (int nt = 0; nt < 4; ++nt)
        s[mt][nt] = __builtin_amdgcn_mfma_f32_16x16x32_bf16(kf[mt], qf[nt],
                                                            s[mt][nt], 0, 0, 0);
    float inv_s[4];
#pragma unroll
    for (int nt = 0; nt < 4; ++nt) {
      float mx = -1e30f;
#pragma unroll
      for (int mt = 0; mt < 4; ++mt) {
        float4 b4 = *(const float4*)&biasf[(h * 64 + nt * 16 + l15) * 64 +
                                           mt * 16 + l4 * 4];
        s[mt][nt][0] = s[mt][nt][0] * scale + b4.x;
        s[mt][nt][1] = s[mt][nt][1] * scale + b4.y;
        s[mt][nt][2] = s[mt][nt][2] * scale + b4.z;
        s[mt][nt][3] = s[mt][nt][3] * scale + b4.w;
#pragma unroll
        for (int r = 0; r < 4; ++r) mx = fmaxf(mx, s[mt][nt][r]);
      }
      mx = fmaxf(mx, __shfl_xor(mx, 16));
      mx = fmaxf(mx, __shfl_xor(mx, 32));
      float sum = 0.f;
#pragma unroll
      for (int mt = 0; mt < 4; ++mt)
#pragma unroll
        for (int r = 0; r < 4; ++r) {
          float e = __expf(s[mt][nt][r] - mx);
          s[mt][nt][r] = e;
          sum += e;
        }
      sum += __shfl_xor(sum, 16);
      sum += __shfl_xor(sum, 32);
      inv_s[nt] = 1.f / sum;
    }
#pragma unroll
    for (int i = 0; i < 4; ++i)
#pragma unroll
      for (int dt = 0; dt < 2; ++dt)
        (hh ? o1 : o0)[i][dt] = (f32x4){0.f, 0.f, 0.f, 0.f};
#pragma unroll
    for (int ks = 0; ks < 2; ++ks) {
#pragma unroll
      for (int nt = 0; nt < 4; ++nt)
#pragma unroll
        for (int mh = 0; mh < 2; ++mh) {
          const int mt = 2 * ks + mh;
          ushort4 pk = make_ushort4(f2bf(s[mt][nt][0] * inv_s[nt]),
                                    f2bf(s[mt][nt][1] * inv_s[nt]),
                                    f2bf(s[mt][nt][2] * inv_s[nt]),
                                    f2bf(s[mt][nt][3] * inv_s[nt]));
          *(ushort4*)&ph[(nt * 16 + l15) * 36 + mh * 16 + l4 * 4] = pk;
        }
      bf16x8 pa[4], vf[2];
#pragma unroll
      for (int i = 0; i < 4; ++i) {
        const unsigned short* pp = &ph[(i * 16 + l15) * 36 + l4 * 8];
        union { bf16x8 v; ushort4 u[2]; } tmp;
        tmp.u[0] = *(const ushort4*)pp;
        tmp.u[1] = *(const ushort4*)(pp + 4);
        pa[i] = tmp.v;
      }
#pragma unroll
      for (int dt = 0; dt < 2; ++dt) {
        const unsigned short* vp = &vT[(dt * 16 + l15) * 68 + ks * 32 + l4 * 8];
        union { bf16x8 v; ushort4 u[2]; } tmp;
        tmp.u[0] = *(const ushort4*)vp;
        tmp.u[1] = *(const ushort4*)(vp + 4);
        vf[dt] = tmp.v;
      }
#pragma unroll
      for (int i = 0; i < 4; ++i)
#pragma unroll
        for (int dt = 0; dt < 2; ++dt)
          (hh ? o1 : o0)[i][dt] = __builtin_amdgcn_mfma_f32_16x16x32_bf16(
              pa[i], vf[dt], (hh ? o1 : o0)[i][dt], 0, 0, 0);
    }
  }
  __syncthreads();
  unsigned short* xattO = smem;
#pragma unroll
  for (int hh = 0; hh < 2; ++hh) {
    const int h = wave * 2 + hh;
#pragma unroll
    for (int i = 0; i < 4; ++i)
#pragma unroll
      for (int dt = 0; dt < 2; ++dt)
#pragma unroll
        for (int r = 0; r < 4; ++r)
          xattO[(i * 16 + l4 * 4 + r) * 264 + h * 32 + dt * 16 + l15] =
              f2bf((hh ? o1 : o0)[i][dt][r]);
  }
  __syncthreads();
  {
    f32x4 a4[4];
#pragma unroll
    for (int n = 0; n < 4; ++n) a4[n] = (f32x4){0.f, 0.f, 0.f, 0.f};
#pragma unroll
    for (int ks = 0; ks < 8; ++ks) {
      bf16x8 af = *(const bf16x8*)&xattO[(wave * 16 + l15) * 264 + ks * 32 + l4 * 8];
#pragma unroll
      for (int n = 0; n < 4; ++n) {
        bf16x8 bfr = *(const bf16x8*)&siw1t[(n * 16 + l15) * 256 + ks * 32 + l4 * 8];
        a4[n] = __builtin_amdgcn_mfma_f32_16x16x32_bf16(af, bfr, a4[n], 0, 0, 0);
      }
    }
    float part[4] = {0.f, 0.f, 0.f, 0.f};
#pragma unroll
    for (int n = 0; n < 4; ++n) {
      const int j = n * 16 + l15;
      const float sc4 = g4[j] * rsqrtf(v4[j] + EPS);
      const float m4j = m4[j], b4j = b4v[j], bij = bi1[j], w2j = w2[j];
#pragma unroll
      for (int r = 0; r < 4; ++r)
        part[r] += gelu_exact((a4[n][r] + bij - m4j) * sc4 + b4j) * w2j;
    }
#pragma unroll
    for (int r = 0; r < 4; ++r) {
      part[r] += __shfl_xor(part[r], 1);
      part[r] += __shfl_xor(part[r], 2);
      part[r] += __shfl_xor(part[r], 4);
      part[r] += __shfl_xor(part[r], 8);
    }
    if (l15 == 0) {
      const float b2v = bi2[0];
#pragma unroll
      for (int r = 0; r < 4; ++r)
        sig[wave * 16 + l4 * 4 + r] = 1.f / (1.f + expf(-(part[r] + b2v)));
    }
  }
  __syncthreads();
  {
    const int p = tid >> 2, l = tid & 3;
    float s = 0.f, sq = 0.f;
#pragma unroll
    for (int k = 0; k < 16; ++k) {
      ushort4 u = *(const ushort4*)&xattO[p * 264 + l * 4 + k * 16];
      float x0 = bf2f(u.x), x1 = bf2f(u.y), x2 = bf2f(u.z), x3 = bf2f(u.w);
      s += x0 + x1 + x2 + x3;
      sq += x0 * x0 + x1 * x1 + x2 * x2 + x3 * x3;
    }
    s += __shfl_xor(s, 1);  sq += __shfl_xor(sq, 1);
    s += __shfl_xor(s, 2);  sq += __shfl_xor(sq, 2);
    const float mean = s * (1.f / 256.f);
    const float var = sq * (1.f / 256.f) - mean * mean;
    const float rstd = rsqrtf(var + EPS);
    const size_t orow = ((size_t)w * 64 + p) * 512;
    const float sg = sig[p];
#pragma unroll
    for (int k = 0; k < 16; ++k) {
      const int c = l * 4 + k * 16;
      ushort4 u = *(const ushort4*)&xattO[p * 264 + c];
      *(ushort4*)&outc[orow + c] = make_ushort4(
          f2bf((bf2f(u.x) - mean) * rstd * glno[c + 0] + blno[c + 0]),
          f2bf((bf2f(u.y) - mean) * rstd * glno[c + 1] + blno[c + 1]),
          f2bf((bf2f(u.z) - mean) * rstd * glno[c + 2] + blno[c + 2]),
          f2bf((bf2f(u.w) - mean) * rstd * glno[c + 3] + blno[c + 3]));
      ushort4 pu = *(const ushort4*)&xpj[((size_t)w * 64 + p) * 256 + c];
      float sc0 = g3[c + 0] * rsqrtf(v3[c + 0] + EPS);
      float sc1 = g3[c + 1] * rsqrtf(v3[c + 1] + EPS);
      float sc2 = g3[c + 2] * rsqrtf(v3[c + 2] + EPS);
      float sc3 = g3[c + 3] * rsqrtf(v3[c + 3] + EPS);
      *(ushort4*)&outc[orow + 256 + c] = make_ushort4(
          f2bf(sg * bf2f(pu.x) * sc0 + (b3v[c + 0] - m3[c + 0] * sc0)),
          f2bf(sg * bf2f(pu.y) * sc1 + (b3v[c + 1] - m3[c + 1] * sc1)),
          f2bf(sg * bf2f(pu.z) * sc2 + (b3v[c + 2] - m3[c + 2] * sc2)),
          f2bf(sg * bf2f(pu.w) * sc3 + (b3v[c + 3] - m3[c + 3] * sc3)));
    }
  }
}

// ---------------------------------------------------------------------------
extern "C" void kernel_launch(void* const* d_in, const int* in_sizes, int n_in,
                              void* d_out, int out_size, void* d_ws, size_t ws_size,
                              hipStream_t stream) {
  const float* x     = (const float*)d_in[0];
  const float* w_pa  = (const float*)d_in[1];
  const float* b_pa  = (const float*)d_in[2];
  const float* g_lna = (const float*)d_in[3];
  const float* b_lna = (const float*)d_in[4];
  const float* w_pc  = (const float*)d_in[5];
  const float* b_pc  = (const float*)d_in[6];
  const float* g_lnc = (const float*)d_in[7];
  const float* b_lnc = (const float*)d_in[8];
  const float* dw_w  = (const float*)d_in[9];
  const float* dw_b  = (const float*)d_in[10];
  const float* g_bn1 = (const float*)d_in[11];
  const float* b_bn1 = (const float*)d_in[12];
  const float* m_bn1 = (const float*)d_in[13];
  const float* v_bn1 = (const float*)d_in[14];
  const float* ci_w1 = (const float*)d_in[15];
  const float* ci_b1 = (const float*)d_in[16];
  const float* g_bn2 = (const float*)d_in[17];
  const float* b_bn2 = (const float*)d_in[18];
  const float* m_bn2 = (const float*)d_in[19];
  const float* v_bn2 = (const float*)d_in[20];
  const float* ci_w2 = (const float*)d_in[21];
  const float* ci_b2 = (const float*)d_in[22];
  const float* pj_w  = (const float*)d_in[23];
  const float* pj_b  = (const float*)d_in[24];
  const float* g_bn3 = (const float*)d_in[25];
  const float* b_bn3 = (const float*)d_in[26];
  const float* m_bn3 = (const float*)d_in[27];
  const float* v_bn3 = (const float*)d_in[28];
  const float* w_qkv = (const float*)d_in[29];
  const float* b_qkv = (const float*)d_in[30];
  const float* si_w1 = (const float*)d_in[31];
  const float* si_b1 = (const float*)d_in[32];
  const float* g_bn4 = (const float*)d_in[33];
  const float* b_bn4 = (const float*)d_in[34];
  const float* m_bn4 = (const float*)d_in[35];
  const float* v_bn4 = (const float*)d_in[36];
  const float* si_w2 = (const float*)d_in[37];
  const float* si_b2 = (const float*)d_in[38];
  const float* g_lno = (const float*)d_in[39];
  const float* b_lno = (const float*)d_in[40];
  const float* w_out = (const float*)d_in[41];
  const float* b_out = (const float*)d_in[42];
  const float* rpb   = (const float*)d_in[43];
  const int*   rel   = (const int*)d_in[44];

  char* ws = (char*)d_ws;
  unsigned short* G12BF = (unsigned short*)(ws + 0);            // (M,768)
  unsigned short* QKVBF = (unsigned short*)(ws + 0);            // (M,768)
  unsigned short* A1BF  = (unsigned short*)(ws + 154140672ull); // (M,256)
  unsigned short* C1BF  = (unsigned short*)(ws + 205520896ull); // (M,512)
  unsigned short* CAT   = (unsigned short*)(ws + 205520896ull); // (M,512)
  unsigned short* XBF   = (unsigned short*)(ws + 308281344ull); // (M,512)
  unsigned short* CVBF  = (unsigned short*)(ws + 308281344ull); // (M,512)
  unsigned short* PJBF  = (unsigned short*)(ws + 411041792ull); // (M,256)
  float*          CIP   = (float*)(ws + 462422016ull);          // (1568,512)
  float*          CIM   = (float*)(ws + 465633280ull);          // (2,512)
  float*          GATE  = (float*)(ws + 465637376ull);          // (2,256)
  float*          B12   = (float*)(ws + 465639424ull);          // (768)
  float*          BIASF = (float*)(ws + 465642496ull);          // (8,64,64)
  unsigned short* WT    = (unsigned short*)(ws + 465773568ull);
  unsigned short* WpaT  = WT + 0;        // (256,512)
  unsigned short* WpcT  = WT + 131072;   // (512,512)
  unsigned short* PjT   = WT + 393216;   // (256,512)
  unsigned short* QkvT  = WT + 524288;   // (768,256)
  unsigned short* OutT  = WT + 720896;   // (512,512)
  unsigned short* SiT   = WT + 983040;   // (64,256)

  const int M = MROWS;
  dim3 b256(256), b512(512);

  // 0) fused prep + x->bf16
  prep_all<<<3923, b256, 0, stream>>>(w_pa, w_pc, pj_w, w_qkv, w_out, si_w1,
                                      b_pa, b_pc, rpb, rel,
                                      WpaT, WpcT, PjT, QkvT, OutT, SiT,
                                      B12, BIASF);
  cvt_bf16<<<(M * 512 / 8 + 255) / 256, b256, 0, stream>>>(x, XBF, M * 512 / 8);

  // 1+2) fused input GEMM: [x@w_pa | x@w_pc] -> G12BF (M,768)
  gemm256<true><<<dim3(3, M / 256), dim3(512), 0, stream>>>(XBF, WpaT, B12, G12BF,
                                                            M, 768, 512);
  ln_dual<<<M / 4, b256, 0, stream>>>(G12BF, A1BF, C1BF, g_lna, b_lna, g_lnc, b_lnc);

  // 3) depthwise conv + BN1 + GELU + channel sums (XBF dead -> CVBF)
  dwconv_bn_gelu<<<NWIN, b256, 0, stream>>>(C1BF, dw_w, dw_b, g_bn1, b_bn1, m_bn1,
                                            v_bn1, CVBF, CIP);
  ci_reduce<<<2, b512, 0, stream>>>(CIP, CIM);
  ci_gate<<<1, b512, 0, stream>>>(CIM, ci_w1, ci_b1, g_bn2, b_bn2, m_bn2, v_bn2,
                                  ci_w2, ci_b2, GATE);

  // 4) pj GEMM (bf16 out)
  gemm256<true><<<dim3(1, M / 256), dim3(512), 0, stream>>>(CVBF, PjT, pj_b, PJBF,
                                                            M, 256, 512);

  // 5) qkv GEMM (bf16 out; G12BF dead -> QKVBF)
  gemm256<true><<<dim3(3, M / 256), dim3(512), 0, stream>>>(A1BF, QkvT, b_qkv, QKVBF,
                                                            M, 768, 256);

  // 6) fused attention + si gate + BN3 + LN + concat (C1BF dead -> CAT)
  attn_si<<<NWIN, b256, 0, stream>>>(QKVBF, PJBF, GATE, BIASF, SiT,
                                     si_b1, g_bn4, b_bn4, m_bn4, v_bn4,
                                     si_w2, si_b2,
                                     g_bn3, b_bn3, m_bn3, v_bn3,
                                     g_lno, b_lno, CAT);

  // 7) final GEMM -> d_out (f32)
  gemm256<false><<<dim3(2, M / 256), dim3(512), 0, stream>>>(CAT, OutT, b_out,
                                                             (float*)d_out, M, 512, 512);
}